// Round 12
// baseline (363.250 us; speedup 1.0000x reference)
//
#include <hip/hip_runtime.h>
#include <math.h>

typedef __bf16 bf16x8 __attribute__((ext_vector_type(8)));
typedef __bf16 bf16x4 __attribute__((ext_vector_type(4)));
typedef float  f32x16 __attribute__((ext_vector_type(16)));

static __device__ __forceinline__ f32x16 zero16() {
  f32x16 v;
  #pragma unroll
  for (int i = 0; i < 16; ++i) v[i] = 0.f;
  return v;
}
static __device__ __forceinline__ unsigned int bfbits(__bf16 b) {
  return (unsigned int)__builtin_bit_cast(unsigned short, b);
}
static __device__ __forceinline__ bf16x8 mk8(unsigned int a, unsigned int b,
                                             unsigned int c, unsigned int d) {
  uint4 t; t.x = a; t.y = b; t.z = c; t.w = d;
  return __builtin_bit_cast(bf16x8, t);
}

// ---- consumer-side BN finalize: every block reduces producer partials -> ss in LDS ----
// partials layout: [blk][2*COUTT], blk % CSPLITP = channel-group. Deterministic (same
// order as the old k_finalize2, double accumulation).
template<int C, int CSPLITP>
static __device__ __forceinline__ void block_finalize(const float* __restrict__ partials,
    int nblk, double inv_n, const float* __restrict__ g, const float* __restrict__ be,
    float* __restrict__ ssl, double* __restrict__ red) {
  const int COUTT = C/CSPLITP;
  const int NSTAT = 2*C;
  const int PER = 256/NSTAT;
  int tid = threadIdx.x;
  int st = tid % NSTAT, sub = tid / NSTAT;
  int c = st % C, kind = st / C;
  int cq = c / COUTT, j = c % COUTT;
  int nb = nblk / CSPLITP;
  double acc = 0.0;
  #pragma unroll 4
  for (int i = sub; i < nb; i += PER)
    acc += (double)partials[(size_t)(cq + i*CSPLITP)*2*COUTT + kind*COUTT + j];
  red[tid] = acc;
  __syncthreads();
  for (int off = PER>>1; off > 0; off >>= 1) {
    if (sub < off) red[tid] += red[tid + off*NSTAT];
    __syncthreads();
  }
  if (tid < C) {
    double mean = red[tid]*inv_n;
    double var  = red[C+tid]*inv_n - mean*mean;
    float scale = g[tid] * rsqrtf((float)var + 1e-3f);
    ssl[tid] = scale;
    ssl[C+tid] = be[tid] - (float)mean*scale;
  }
  __syncthreads();
}

// ---------------- conv1: 1x1 stride2, 3->16, fused BN batch-stats partials ----------------
__global__ __launch_bounds__(256) void k_conv1(const float* __restrict__ x,
    const float* __restrict__ w, const float* __restrict__ b, float* __restrict__ y,
    float* __restrict__ partials) {
  int t = blockIdx.x*256 + threadIdx.x;        // 16*128*128 pixels
  int ox = t & 127, oy = (t >> 7) & 127, bb = t >> 14;
  const float* xp = x + ((size_t)((bb*256 + 2*oy)*256 + 2*ox))*3;
  float x0 = xp[0], x1 = xp[1], x2 = xp[2];
  float4 rg[4];
  float4* yp = (float4*)(y + (size_t)t*16);
  #pragma unroll
  for (int g = 0; g < 4; ++g) {
    float4 r;
    r.x = b[g*4+0] + x0*w[g*4+0] + x1*w[16+g*4+0] + x2*w[32+g*4+0];
    r.y = b[g*4+1] + x0*w[g*4+1] + x1*w[16+g*4+1] + x2*w[32+g*4+1];
    r.z = b[g*4+2] + x0*w[g*4+2] + x1*w[16+g*4+2] + x2*w[32+g*4+2];
    r.w = b[g*4+3] + x0*w[g*4+3] + x1*w[16+g*4+3] + x2*w[32+g*4+3];
    rg[g] = r;
    yp[g] = r;
  }
  float4 s4[4], q4[4];
  #pragma unroll
  for (int g=0; g<4; ++g) {
    s4[g] = rg[g];
    q4[g] = make_float4(rg[g].x*rg[g].x, rg[g].y*rg[g].y, rg[g].z*rg[g].z, rg[g].w*rg[g].w);
  }
  #pragma unroll
  for (int off=1; off<64; off<<=1) {
    #pragma unroll
    for (int g=0; g<4; ++g) {
      s4[g].x += __shfl_xor(s4[g].x, off); s4[g].y += __shfl_xor(s4[g].y, off);
      s4[g].z += __shfl_xor(s4[g].z, off); s4[g].w += __shfl_xor(s4[g].w, off);
      q4[g].x += __shfl_xor(q4[g].x, off); q4[g].y += __shfl_xor(q4[g].y, off);
      q4[g].z += __shfl_xor(q4[g].z, off); q4[g].w += __shfl_xor(q4[g].w, off);
    }
  }
  __shared__ float red[4][32];
  int wv = threadIdx.x >> 6, lane = threadIdx.x & 63;
  if (lane == 0) {
    #pragma unroll
    for (int g=0; g<4; ++g) {
      *(float4*)&red[wv][g*4]      = s4[g];
      *(float4*)&red[wv][16 + g*4] = q4[g];
    }
  }
  __syncthreads();
  if (threadIdx.x < 32)
    partials[(size_t)blockIdx.x*32 + threadIdx.x] =
      red[0][threadIdx.x]+red[1][threadIdx.x]+red[2][threadIdx.x]+red[3][threadIdx.x];
}

// ---------------- finalize (kept only for the last BN, before convt_final) -------------
template<int C,int CSPLIT>
__global__ __launch_bounds__(256) void k_finalize2(const float* __restrict__ partials, int nblk,
    double inv_n, const float* __restrict__ g, const float* __restrict__ be, float* __restrict__ ss) {
  const int COUTT = C/CSPLIT;
  const int NSTAT = 2*C;
  const int PER = 256/NSTAT;
  __shared__ double red[256];
  int tid = threadIdx.x;
  int st = tid % NSTAT, sub = tid / NSTAT;
  int c = st % C, kind = st / C;
  int cq = c / COUTT, j = c % COUTT;
  int nb = nblk / CSPLIT;
  double acc = 0.0;
  #pragma unroll 4
  for (int i = sub; i < nb; i += PER) {
    int bq = cq + i*CSPLIT;
    acc += (double)partials[(size_t)bq*2*COUTT + kind*COUTT + j];
  }
  red[tid] = acc;
  __syncthreads();
  for (int off = PER>>1; off > 0; off >>= 1) {
    if (sub < off) red[tid] += red[tid + off*NSTAT];
    __syncthreads();
  }
  if (tid < C) {
    double mean = red[tid]*inv_n;
    double var  = red[C+tid]*inv_n - mean*mean;
    float scale = g[tid] * rsqrtf((float)var + 1e-3f);
    float shift = be[tid] - (float)mean*scale;
    ss[tid] = scale; ss[C+tid] = shift;
  }
}

// ---- forward 3x3 stride-2 SAME conv, self-finalized input BN+ReLU + fused stats ----
template<int CIN,int COUT,int CSPLIT,int HIN,int HOUT,int CP,int CSPLITP>
__global__ __launch_bounds__(256) void k_conv_bn(const float* __restrict__ in,
    const float* __restrict__ w, const float* __restrict__ bias,
    const float* __restrict__ pin, const float* __restrict__ g, const float* __restrict__ be,
    double inv_n, int nblk, float* __restrict__ y, float* __restrict__ partials) {
  const int COUTT = COUT/CSPLIT;
  const int NW4 = COUTT/4;
  __shared__ float4 wlds[9*CIN*NW4];
  __shared__ double fred[256];
  __shared__ __align__(16) float ssl[2*CIN];
  int bid = blockIdx.x;
  int cq  = bid % CSPLIT;
  int pxb = bid / CSPLIT;
  int c0  = cq*COUTT;
  for (int e = threadIdx.x; e < 9*CIN*NW4; e += 256) {
    int r = e / NW4, cg = e % NW4;
    wlds[e] = *(const float4*)(w + (size_t)r*COUT + c0 + cg*4);
  }
  block_finalize<CP,CSPLITP>(pin, nblk, inv_n, g, be, ssl, fred);  // also fences wlds
  int t0 = pxb*256 + threadIdx.x;
  float4 acc[NW4];
  #pragma unroll
  for (int gg=0; gg<NW4; ++gg) acc[gg] = *(const float4*)(bias + c0 + gg*4);
  int ox = t0 % HOUT, oy = (t0/HOUT) % HOUT, bb = t0/(HOUT*HOUT);
  #pragma unroll 1
  for (int dy=0; dy<3; ++dy) {
    #pragma unroll 1
    for (int dx=0; dx<3; ++dx) {
      int tap = dy*3+dx;
      int iy = 2*oy + dy, ix = 2*ox + dx;
      if (iy < HIN && ix < HIN) {
        const float* bp = in + ((size_t)(bb*HIN + iy)*HIN + ix)*CIN;
        #pragma unroll
        for (int ci4=0; ci4<CIN/4; ++ci4) {
          float4 v = *(const float4*)(bp + ci4*4);
          float4 sc = *(const float4*)(ssl + ci4*4);
          float4 sh = *(const float4*)(ssl + CIN + ci4*4);
          v.x = fmaxf(0.f, fmaf(v.x, sc.x, sh.x));
          v.y = fmaxf(0.f, fmaf(v.y, sc.y, sh.y));
          v.z = fmaxf(0.f, fmaf(v.z, sc.z, sh.z));
          v.w = fmaxf(0.f, fmaf(v.w, sc.w, sh.w));
          float va[4] = {v.x, v.y, v.z, v.w};
          #pragma unroll
          for (int k=0;k<4;++k) {
            float vk = va[k];
            #pragma unroll
            for (int gg=0; gg<NW4; ++gg) {
              float4 w4 = wlds[(tap*CIN + ci4*4 + k)*NW4 + gg];
              acc[gg].x = fmaf(vk, w4.x, acc[gg].x);
              acc[gg].y = fmaf(vk, w4.y, acc[gg].y);
              acc[gg].z = fmaf(vk, w4.z, acc[gg].z);
              acc[gg].w = fmaf(vk, w4.w, acc[gg].w);
            }
          }
        }
      }
    }
  }
  float4* yp = (float4*)(y + (size_t)t0*COUT + c0);
  #pragma unroll
  for (int gg=0;gg<NW4;++gg) yp[gg] = acc[gg];
  float4 s4[NW4], q4[NW4];
  #pragma unroll
  for (int gg=0; gg<NW4; ++gg) {
    s4[gg] = acc[gg];
    q4[gg] = make_float4(acc[gg].x*acc[gg].x, acc[gg].y*acc[gg].y,
                         acc[gg].z*acc[gg].z, acc[gg].w*acc[gg].w);
  }
  #pragma unroll
  for (int off=1; off<64; off<<=1) {
    #pragma unroll
    for (int gg=0; gg<NW4; ++gg) {
      s4[gg].x += __shfl_xor(s4[gg].x, off); s4[gg].y += __shfl_xor(s4[gg].y, off);
      s4[gg].z += __shfl_xor(s4[gg].z, off); s4[gg].w += __shfl_xor(s4[gg].w, off);
      q4[gg].x += __shfl_xor(q4[gg].x, off); q4[gg].y += __shfl_xor(q4[gg].y, off);
      q4[gg].z += __shfl_xor(q4[gg].z, off); q4[gg].w += __shfl_xor(q4[gg].w, off);
    }
  }
  __shared__ float red2[4][2*COUTT];
  int wv = threadIdx.x >> 6, lane = threadIdx.x & 63;
  __syncthreads();
  if (lane == 0) {
    #pragma unroll
    for (int gg=0; gg<NW4; ++gg) {
      *(float4*)&red2[wv][gg*4]         = s4[gg];
      *(float4*)&red2[wv][COUTT + gg*4] = q4[gg];
    }
  }
  __syncthreads();
  if (threadIdx.x < 2*COUTT)
    partials[(size_t)bid*2*COUTT + threadIdx.x] =
      red2[0][threadIdx.x]+red2[1][threadIdx.x]+red2[2][threadIdx.x]+red2[3][threadIdx.x];
}

// ================= memory module (MFMA 32x32x16, two-pass, u=exp stored bf16) ==========

// fused prep: blocks [0,128) pack mem; blocks [128,1152) self-finalize BN3 + pack z
__global__ __launch_bounds__(256) void k_prep_mz(const float* __restrict__ mem,
    const float* __restrict__ y3, const float* __restrict__ pin,
    const float* __restrict__ g, const float* __restrict__ be,
    __bf16* __restrict__ MH, __bf16* __restrict__ ML,
    __bf16* __restrict__ M2H, __bf16* __restrict__ M2L, __bf16* __restrict__ MHT,
    __bf16* __restrict__ ZH, __bf16* __restrict__ ZL,
    __bf16* __restrict__ Z2H, __bf16* __restrict__ Z2L) {
  __shared__ double fred[256];
  __shared__ __align__(16) float ssl[128];
  if (blockIdx.x < 128) {
    int t = blockIdx.x*256 + threadIdx.x;   // 2048*16
    int n = t >> 4, c0 = (t & 15)*4;
    float4 v = make_float4(0.f,0.f,0.f,0.f);
    if (n < 2000) v = *(const float4*)(mem + (size_t)n*64 + c0);
    float vv[4] = {v.x, v.y, v.z, v.w};
    bf16x4 h, l, h2, l2;
    #pragma unroll
    for (int i=0;i<4;++i) {
      float f = vv[i];
      __bf16 hb = (__bf16)f;
      h[i] = hb; l[i] = (__bf16)(f - (float)hb);
      float q = f*f;
      __bf16 qb = (__bf16)q;
      h2[i] = qb; l2[i] = (__bf16)(q - (float)qb);
    }
    *(bf16x4*)(MH  + (size_t)n*64 + c0) = h;
    *(bf16x4*)(ML  + (size_t)n*64 + c0) = l;
    *(bf16x4*)(M2H + (size_t)n*64 + c0) = h2;
    *(bf16x4*)(M2L + (size_t)n*64 + c0) = l2;
    #pragma unroll
    for (int i=0;i<4;++i) MHT[(size_t)(c0+i)*2048 + n] = h[i];
  } else {
    block_finalize<64,8>(pin, 512, 1.0/16384.0, g, be, ssl, fred);
    int t = (blockIdx.x - 128)*256 + threadIdx.x;   // handles 4 elems
    float4 v = ((const float4*)y3)[t];
    int c0 = (t*4) & 63;
    float4 sc = *(const float4*)(ssl + c0);
    float4 sh = *(const float4*)(ssl + 64 + c0);
    float vv[4];
    vv[0] = fmaxf(0.f, fmaf(v.x, sc.x, sh.x));
    vv[1] = fmaxf(0.f, fmaf(v.y, sc.y, sh.y));
    vv[2] = fmaxf(0.f, fmaf(v.z, sc.z, sh.z));
    vv[3] = fmaxf(0.f, fmaf(v.w, sc.w, sh.w));
    bf16x4 h, l, h2, l2;
    #pragma unroll
    for (int i=0;i<4;++i) {
      float f = vv[i];
      __bf16 hb = (__bf16)f;
      h[i] = hb; l[i] = (__bf16)(f - (float)hb);
      float q = f*f;
      __bf16 qb = (__bf16)q;
      h2[i] = qb; l2[i] = (__bf16)(q - (float)qb);
    }
    ((bf16x4*)ZH)[t] = h;  ((bf16x4*)ZL)[t] = l;
    ((bf16x4*)Z2H)[t] = h2; ((bf16x4*)Z2L)[t] = l2;
  }
}

// pass1: scores via MFMA; per-tile INDEPENDENT softmax partials; stores u=exp(s-tmax) bf16
// + per-tile max MT + chunk partials. 4-wave blocks; chunk-staggered blockIdx.
__global__ __launch_bounds__(256) void k_pass1(
    const __bf16* __restrict__ ZH, const __bf16* __restrict__ ZL,
    const __bf16* __restrict__ Z2H, const __bf16* __restrict__ Z2L,
    const __bf16* __restrict__ MH, const __bf16* __restrict__ ML,
    const __bf16* __restrict__ M2H, const __bf16* __restrict__ M2L,
    __bf16* __restrict__ U, float* __restrict__ MT,
    float* __restrict__ partM, float* __restrict__ partS) {
  int chunk = blockIdx.x & 15, pbg = blockIdx.x >> 4;   // 16 chunks x 128 p-groups
  int wave = threadIdx.x >> 6, lane = threadIdx.x & 63;
  int p0 = pbg*128 + wave*32;
  int col = lane & 31, hi = lane >> 5;
  bf16x8 bzh[4], bzl[4], b2h[4], b2l[4];
  size_t zoff = (size_t)(p0 + col)*64 + hi*8;
  #pragma unroll
  for (int ks=0;ks<4;++ks) {
    bzh[ks] = *(const bf16x8*)(ZH  + zoff + ks*16);
    bzl[ks] = *(const bf16x8*)(ZL  + zoff + ks*16);
    b2h[ks] = *(const bf16x8*)(Z2H + zoff + ks*16);
    b2l[ks] = *(const bf16x8*)(Z2L + zoff + ks*16);
  }
  float tmaxv[4], ssumv[4];
  int nbase = chunk*128;
  #pragma unroll
  for (int t=0; t<4; ++t) {
    int n0 = nbase + t*32;
    size_t arow = (size_t)(n0 + col)*64 + hi*8;
    f32x16 num = zero16(), den = zero16();
    #pragma unroll
    for (int ks=0;ks<4;++ks) {
      bf16x8 amh = *(const bf16x8*)(MH + arow + ks*16);
      bf16x8 aml = *(const bf16x8*)(ML + arow + ks*16);
      num = __builtin_amdgcn_mfma_f32_32x32x16_bf16(amh, bzh[ks], num, 0,0,0);
      num = __builtin_amdgcn_mfma_f32_32x32x16_bf16(amh, bzl[ks], num, 0,0,0);
      num = __builtin_amdgcn_mfma_f32_32x32x16_bf16(aml, bzh[ks], num, 0,0,0);
      bf16x8 a2h = *(const bf16x8*)(M2H + arow + ks*16);
      bf16x8 a2l = *(const bf16x8*)(M2L + arow + ks*16);
      den = __builtin_amdgcn_mfma_f32_32x32x16_bf16(a2h, b2h[ks], den, 0,0,0);
      den = __builtin_amdgcn_mfma_f32_32x32x16_bf16(a2h, b2l[ks], den, 0,0,0);
      den = __builtin_amdgcn_mfma_f32_32x32x16_bf16(a2l, b2h[ks], den, 0,0,0);
    }
    bool maskt = (n0 + 32 > 2000);
    float sv[16];
    float tmax = -3.4e38f;
    #pragma unroll
    for (int r=0;r<16;++r) {
      float s = (num[r] + 1e-12f) * __builtin_amdgcn_rcpf(den[r] + 1e-12f);
      if (maskt) {
        int nn = n0 + (r&3) + 8*(r>>2) + 4*hi;
        if (nn >= 2000) s = -3.4e38f;
      }
      sv[r] = s;
      tmax = fmaxf(tmax, s);
    }
    float ssum = 0.f;
    unsigned int up[8];
    #pragma unroll
    for (int j=0;j<8;++j) {
      float u0 = __expf(sv[2*j]   - tmax);
      float u1 = __expf(sv[2*j+1] - tmax);
      ssum += u0; ssum += u1;
      up[j] = bfbits((__bf16)u0) | (bfbits((__bf16)u1) << 16);
    }
    size_t idx = (size_t)((chunk*4 + t)*16384 + p0 + col)*2 + hi;
    uint4 st0; st0.x = up[0]; st0.y = up[1]; st0.z = up[2]; st0.w = up[3];
    uint4 st1; st1.x = up[4]; st1.y = up[5]; st1.z = up[6]; st1.w = up[7];
    *(uint4*)(U + idx*16)     = st0;
    *(uint4*)(U + idx*16 + 8) = st1;
    MT[idx] = tmax;
    tmaxv[t] = tmax; ssumv[t] = ssum;
  }
  // combine 4 independent tiles, then the lane-halves
  float m = fmaxf(fmaxf(tmaxv[0], tmaxv[1]), fmaxf(tmaxv[2], tmaxv[3]));
  float S = ssumv[0]*__expf(tmaxv[0]-m) + ssumv[1]*__expf(tmaxv[1]-m)
          + ssumv[2]*__expf(tmaxv[2]-m) + ssumv[3]*__expf(tmaxv[3]-m);
  float mo = __shfl_xor(m, 32);
  float So = __shfl_xor(S, 32);
  float mf = fmaxf(m, mo);
  float Sf = S*__expf(m - mf) + So*__expf(mo - mf);
  if (lane < 32) {
    int p = p0 + col;
    partM[chunk*16384 + p] = mf;
    partS[chunk*16384 + p] = Sf;
  }
}

// pass2 (fused with zcomb): block = 4 waves x 32 p-cols; wave w covers n-tiles 16w..16w+15.
// r = u*exp(mt-CM) thresholded; zhat via MFMA (m-hi only); LDS-reduce 4 waves -> Gz fp32.
__global__ __launch_bounds__(256) void k_pass2(
    const __bf16* __restrict__ U, const float* __restrict__ MT,
    const __bf16* __restrict__ MHT,
    const float* __restrict__ partM, const float* __restrict__ partS,
    float* __restrict__ Gz) {
  __shared__ float zl[4][32][68];
  int pbg = blockIdx.x;                   // 512 p-groups of 32
  int wave = threadIdx.x >> 6, lane = threadIdx.x & 63;
  int p0 = pbg*32;
  int col = lane & 31, hi = lane >> 5;
  int p = p0 + col;
  float pmv[16];
  float Mp = -3.4e38f;
  #pragma unroll
  for (int c=0;c<16;++c) { pmv[c] = partM[c*16384 + p]; Mp = fmaxf(Mp, pmv[c]); }
  float Ssum = 0.f;
  #pragma unroll
  for (int c=0;c<16;++c) Ssum += partS[c*16384 + p] * __expf(pmv[c] - Mp);
  float CM  = Mp + __logf(Ssum);
  float thr = CM - 7.6009025f;     // + ln(1/2000)
  f32x16 za0 = zero16(), za1 = zero16();
  #pragma unroll 2
  for (int t=0; t<16; ++t) {
    int tg = wave*16 + t;
    int n0 = tg*32;
    size_t idx = (size_t)(tg*16384 + p)*2 + hi;
    uint4 a = *(const uint4*)(U + idx*16);
    uint4 b = *(const uint4*)(U + idx*16 + 8);
    float mt = MT[idx];
    float scale = __expf(mt - CM);
    float thru  = __expf(thr - mt);
    unsigned int ua[8] = {a.x,a.y,a.z,a.w,b.x,b.y,b.z,b.w};
    unsigned int qh[8];
    #pragma unroll
    for (int j=0;j<8;++j) {
      float u0 = __builtin_bit_cast(float, ua[j] << 16);
      float u1 = __builtin_bit_cast(float, ua[j] & 0xffff0000u);
      float r0 = (u0 > thru) ? u0*scale : 0.f;
      float r1 = (u1 > thru) ? u1*scale : 0.f;
      qh[j] = bfbits((__bf16)r0) | (bfbits((__bf16)r1) << 16);
    }
    unsigned int qhp[8];
    #pragma unroll
    for (int i=0;i<8;++i) qhp[i] = (unsigned int)__shfl_xor((int)qh[i], 32);
    bf16x8 f1h = hi ? mk8(qhp[2],qhp[3],qh[2],qh[3]) : mk8(qh[0],qh[1],qhp[0],qhp[1]);
    bf16x8 f2h = hi ? mk8(qhp[6],qhp[7],qh[6],qh[7]) : mk8(qh[4],qh[5],qhp[4],qhp[5]);
    #pragma unroll
    for (int kh=0; kh<2; ++kh) {
      bf16x8 fh = kh ? f2h : f1h;
      size_t bofs = (size_t)col*2048 + n0 + kh*16 + hi*8;
      bf16x8 bmh0 = *(const bf16x8*)(MHT + bofs);
      bf16x8 bmh1 = *(const bf16x8*)(MHT + bofs + (size_t)32*2048);
      za0 = __builtin_amdgcn_mfma_f32_32x32x16_bf16(fh, bmh0, za0, 0,0,0);
      za1 = __builtin_amdgcn_mfma_f32_32x32x16_bf16(fh, bmh1, za1, 0,0,0);
    }
  }
  // stash per-wave partials in LDS
  #pragma unroll
  for (int r=0;r<16;++r) {
    int prow = (r&3) + 8*(r>>2) + 4*hi;
    zl[wave][prow][col]      = za0[r];
    zl[wave][prow][col + 32] = za1[r];
  }
  __syncthreads();
  // reduce 4 waves and write Gz fp32: thread -> (p-local, 8 channels)
  int tp = threadIdx.x >> 3;
  int tc = (threadIdx.x & 7) * 8;
  float4 s0 = make_float4(0.f,0.f,0.f,0.f);
  float4 s1 = make_float4(0.f,0.f,0.f,0.f);
  #pragma unroll
  for (int w2=0; w2<4; ++w2) {
    float4 a0 = *(const float4*)&zl[w2][tp][tc];
    float4 a1 = *(const float4*)&zl[w2][tp][tc+4];
    s0.x += a0.x; s0.y += a0.y; s0.z += a0.z; s0.w += a0.w;
    s1.x += a1.x; s1.y += a1.y; s1.z += a1.z; s1.w += a1.w;
  }
  float* gp = Gz + (size_t)(p0 + tp)*64 + tc;
  *(float4*)gp       = s0;
  *(float4*)(gp + 4) = s1;
}

// ---- conv_transpose 3x3 stride2 SAME, parity-class blocks, self-finalized BN + stats ----
template<int CIN,int COUT,int CSPLIT,int HIN,bool BN,int CP,int CSPLITP>
__global__ __launch_bounds__(256) void k_convt_bn(const float* __restrict__ in,
    const float* __restrict__ w, const float* __restrict__ bias,
    const float* __restrict__ pin, const float* __restrict__ g, const float* __restrict__ be,
    double inv_n, int nblk, float* __restrict__ y, float* __restrict__ partials) {
  const int COUTT = COUT/CSPLIT;
  const int HOUT = 2*HIN;
  __shared__ float4 wlds[4*COUTT*(CIN/4)];
  __shared__ double fred[256];
  __shared__ __align__(16) float ssl[2*CIN];
  int bid = blockIdx.x;
  int cq = bid % CSPLIT; int rest = bid / CSPLIT;
  int cls = rest % 4;    int pxb = rest / 4;
  int pm = cls >> 1, pn = cls & 1;
  int c0 = cq*COUTT;
  int NTI = (pm == 0) ? 2 : 1;
  int NTJ = (pn == 0) ? 2 : 1;
  int NT = NTI*NTJ;
  for (int e = threadIdx.x; e < NT*COUTT*(CIN/4); e += 256) {
    int tl = e / (COUTT*(CIN/4));
    int rem = e % (COUTT*(CIN/4));
    int cc = rem / (CIN/4), ci4 = rem % (CIN/4);
    int ki = pm + 2*(tl / NTJ), kj = pn + 2*(tl % NTJ);
    wlds[e] = *(const float4*)(w + ((size_t)(ki*3+kj)*COUT + c0 + cc)*CIN + ci4*4);
  }
  if constexpr (BN) {
    block_finalize<CP,CSPLITP>(pin, nblk, inv_n, g, be, ssl, fred);
  } else {
    __syncthreads();
  }
  int t0 = pxb*256 + threadIdx.x;
  float acc[COUTT];
  #pragma unroll
  for (int cc=0;cc<COUTT;++cc) acc[cc] = bias[c0+cc];
  int nx = t0 % HIN, my = (t0/HIN) % HIN, bb = t0/(HIN*HIN);
  #pragma unroll 1
  for (int ti=0; ti<NTI; ++ti) {
    #pragma unroll 1
    for (int tj=0; tj<NTJ; ++tj) {
      int tl = ti*NTJ + tj;
      int i = my - ti, j = nx - tj;
      if (i >= 0 && j >= 0) {
        const float* bp = in + ((size_t)(bb*HIN + i)*HIN + j)*CIN;
        #pragma unroll
        for (int ci4=0; ci4<CIN/4; ++ci4) {
          float4 v = *(const float4*)(bp + ci4*4);
          if (BN) {
            float4 sc = *(const float4*)(ssl + ci4*4);
            float4 sh = *(const float4*)(ssl + CIN + ci4*4);
            v.x = fmaxf(0.f, fmaf(v.x, sc.x, sh.x));
            v.y = fmaxf(0.f, fmaf(v.y, sc.y, sh.y));
            v.z = fmaxf(0.f, fmaf(v.z, sc.z, sh.z));
            v.w = fmaxf(0.f, fmaf(v.w, sc.w, sh.w));
          }
          #pragma unroll
          for (int cc=0;cc<COUTT;++cc) {
            float4 w4 = wlds[(tl*COUTT + cc)*(CIN/4) + ci4];
            float a = acc[cc];
            a = fmaf(v.x, w4.x, a);
            a = fmaf(v.y, w4.y, a);
            a = fmaf(v.z, w4.z, a);
            a = fmaf(v.w, w4.w, a);
            acc[cc] = a;
          }
        }
      }
    }
  }
  int m = 2*my + pm, n = 2*nx + pn;
  float* yp = y + ((size_t)(bb*HOUT + m)*HOUT + n)*COUT + c0;
  #pragma unroll
  for (int gg=0;gg<COUTT/4;++gg)
    ((float4*)yp)[gg] = make_float4(acc[gg*4], acc[gg*4+1], acc[gg*4+2], acc[gg*4+3]);
  float s[COUTT], q[COUTT];
  #pragma unroll
  for (int cc=0;cc<COUTT;++cc) { s[cc] = acc[cc]; q[cc] = acc[cc]*acc[cc]; }
  #pragma unroll
  for (int off=1; off<64; off<<=1) {
    #pragma unroll
    for (int cc=0;cc<COUTT;++cc) {
      s[cc] += __shfl_xor(s[cc], off);
      q[cc] += __shfl_xor(q[cc], off);
    }
  }
  __shared__ float red2[4][2*COUTT];
  int wv = threadIdx.x >> 6, lane = threadIdx.x & 63;
  __syncthreads();
  if (lane == 0) {
    #pragma unroll
    for (int cc=0;cc<COUTT;++cc) { red2[wv][cc] = s[cc]; red2[wv][COUTT+cc] = q[cc]; }
  }
  __syncthreads();
  if (threadIdx.x < 2*COUTT)
    partials[(size_t)bid*2*COUTT + threadIdx.x] =
      red2[0][threadIdx.x]+red2[1][threadIdx.x]+red2[2][threadIdx.x]+red2[3][threadIdx.x];
}

// ---------------- final conv_transpose 16->3 + input BN+ReLU + clip ----------------
__global__ __launch_bounds__(256) void k_convt_final(const float* __restrict__ in,
    const float* __restrict__ w, const float* __restrict__ bias,
    const float* __restrict__ ss, float* __restrict__ out) {
  const int CIN=16, HIN=128, HOUT=256;
  __shared__ float4 wlds[4*3*4];     // [tap][c][ci4]
  int cls = blockIdx.x & 3;
  int pxb = blockIdx.x >> 2;
  int pm = cls >> 1, pn = cls & 1;
  int NTI = (pm == 0) ? 2 : 1;
  int NTJ = (pn == 0) ? 2 : 1;
  int NT = NTI*NTJ;
  if (threadIdx.x < NT*3*4) {
    int e = threadIdx.x;
    int tl = e / 12, rem = e % 12;
    int c = rem / 4, ci4 = rem % 4;
    int ki = pm + 2*(tl / NTJ), kj = pn + 2*(tl % NTJ);
    wlds[e] = *(const float4*)(w + ((size_t)(ki*3+kj)*3 + c)*CIN + ci4*4);
  }
  __syncthreads();
  int t = pxb*256 + threadIdx.x;
  int nx = t % HIN, my = (t/HIN) % HIN, bb = t/(HIN*HIN);
  float a0 = bias[0], a1 = bias[1], a2 = bias[2];
  #pragma unroll 1
  for (int ti=0; ti<NTI; ++ti) {
    #pragma unroll 1
    for (int tj=0; tj<NTJ; ++tj) {
      int tl = ti*NTJ + tj;
      int i = my - ti, j = nx - tj;
      if (i >= 0 && j >= 0) {
        const float* bp = in + ((size_t)(bb*HIN + i)*HIN + j)*CIN;
        #pragma unroll
        for (int ci4=0; ci4<4; ++ci4) {
          float4 v = *(const float4*)(bp + ci4*4);
          float4 sc = *(const float4*)(ss + ci4*4);
          float4 sh = *(const float4*)(ss + CIN + ci4*4);
          v.x = fmaxf(0.f, fmaf(v.x, sc.x, sh.x));
          v.y = fmaxf(0.f, fmaf(v.y, sc.y, sh.y));
          v.z = fmaxf(0.f, fmaf(v.z, sc.z, sh.z));
          v.w = fmaxf(0.f, fmaf(v.w, sc.w, sh.w));
          float4 w0 = wlds[(tl*3 + 0)*4 + ci4];
          float4 w1 = wlds[(tl*3 + 1)*4 + ci4];
          float4 w2 = wlds[(tl*3 + 2)*4 + ci4];
          a0 = fmaf(v.x, w0.x, a0); a0 = fmaf(v.y, w0.y, a0);
          a0 = fmaf(v.z, w0.z, a0); a0 = fmaf(v.w, w0.w, a0);
          a1 = fmaf(v.x, w1.x, a1); a1 = fmaf(v.y, w1.y, a1);
          a1 = fmaf(v.z, w1.z, a1); a1 = fmaf(v.w, w1.w, a1);
          a2 = fmaf(v.x, w2.x, a2); a2 = fmaf(v.y, w2.y, a2);
          a2 = fmaf(v.z, w2.z, a2); a2 = fmaf(v.w, w2.w, a2);
        }
      }
    }
  }
  int m = 2*my + pm, n = 2*nx + pn;
  float* op = out + ((size_t)(bb*HOUT + m)*HOUT + n)*3;
  op[0] = fminf(fmaxf(a0, 1e-12f), 1.0f);
  op[1] = fminf(fmaxf(a1, 1e-12f), 1.0f);
  op[2] = fminf(fmaxf(a2, 1e-12f), 1.0f);
}

extern "C" void kernel_launch(void* const* d_in, const int* in_sizes, int n_in,
                              void* d_out, int out_size, void* d_ws, size_t ws_size,
                              hipStream_t stream) {
  const float* x    = (const float*)d_in[0];
  const float* w_e1 = (const float*)d_in[1];
  const float* b_e1 = (const float*)d_in[2];
  const float* g1   = (const float*)d_in[3];
  const float* be1  = (const float*)d_in[4];
  const float* w_e2 = (const float*)d_in[5];
  const float* b_e2 = (const float*)d_in[6];
  const float* g2   = (const float*)d_in[7];
  const float* be2  = (const float*)d_in[8];
  const float* w_e3 = (const float*)d_in[9];
  const float* b_e3 = (const float*)d_in[10];
  const float* g3   = (const float*)d_in[11];
  const float* be3  = (const float*)d_in[12];
  const float* wmem = (const float*)d_in[13];
  const float* w_d1 = (const float*)d_in[14];
  const float* b_d1 = (const float*)d_in[15];
  const float* gt1  = (const float*)d_in[16];
  const float* bet1 = (const float*)d_in[17];
  const float* w_d2 = (const float*)d_in[18];
  const float* b_d2 = (const float*)d_in[19];
  const float* gt2  = (const float*)d_in[20];
  const float* bet2 = (const float*)d_in[21];
  const float* w_d3 = (const float*)d_in[22];
  const float* b_d3 = (const float*)d_in[23];
  float* out = (float*)d_out;

  float* ws = (float*)d_ws;
  // U (u=exp bf16): alive pass1->pass2 only; A/Cc alias its head (disjoint live ranges).
  __bf16* U  = (__bf16*)ws;              // 33,554,432 bf16 = 16,777,216 floats
  float* A   = ws;                       // 4,194,304 (alias: y1 enc / t2 dec)
  float* Cc  = ws + 4194304;             // 2,097,152 (alias: y2 enc / t1 dec)
  float* Gz  = ws + 16777216;            // 1,048,576 zhat
  float* E   = Gz + 1048576 + 8388608;   // 1,048,576 y3 raw
  float* bfbase = E + 1048576;
  __bf16* ZH  = (__bf16*)bfbase;                 // 16384*64 each
  __bf16* ZL  = ZH  + 16384*64;
  __bf16* Z2H = ZL  + 16384*64;
  __bf16* Z2L = Z2H + 16384*64;
  __bf16* MH  = Z2L + 16384*64;                  // 2048*64 each
  __bf16* ML  = MH  + 2048*64;
  __bf16* M2H = ML  + 2048*64;
  __bf16* M2L = M2H + 2048*64;
  __bf16* MHT = M2L + 2048*64;                   // 64*2048
  __bf16* MLT = MHT + 64*2048;                   // (unused)
  float* PTb  = (float*)(MLT + 64*2048);         // 131072 BN partials region
  float* PT1  = PTb;                             // [1024][32]
  float* PT2  = PT1 + 32768;                     // [512][32]
  float* PT3  = PT2 + 16384;                     // [512][16]
  float* PTd1 = PT3 + 8192;                      // [512][32]
  float* PTd2 = PTd1 + 16384;                    // [1024][32]
  float* SS   = PTb + 131072;                    // 256
  float* PM   = SS + 256;                        // 262144 partM [16][16384]
  float* PS   = PM + 262144;                     // 262144 partS
  float* MT   = PS + 262144;                     // 2097152 per-tile max [64][16384][2]
  (void)ws_size; (void)in_sizes; (void)n_in; (void)out_size;

  // ---- encoder (BN finalize fused into consumers) ----
  k_conv1<<<1024,256,0,stream>>>(x, w_e1, b_e1, A, PT1);
  k_conv_bn<16,32,2,128,64,16,1><<<512,256,0,stream>>>(
      A, w_e2, b_e2, PT1, g1, be1, 1.0/262144.0, 1024, Cc, PT2);
  k_conv_bn<32,64,8,64,32,32,2><<<512,256,0,stream>>>(
      Cc, w_e3, b_e3, PT2, g2, be2, 1.0/65536.0, 512, E, PT3);
  // ---- memory addressing ----
  k_prep_mz<<<1152,256,0,stream>>>(wmem, E, PT3, g3, be3,
      MH, ML, M2H, M2L, MHT, ZH, ZL, Z2H, Z2L);
  k_pass1<<<2048,256,0,stream>>>(ZH, ZL, Z2H, Z2L, MH, ML, M2H, M2L, U, MT, PM, PS);
  k_pass2<<<512,256,0,stream>>>(U, MT, MHT, PM, PS, Gz);
  // ---- decoder ----
  k_convt_bn<64,32,2,32,false,16,1><<<512,256,0,stream>>>(
      Gz, w_d1, b_d1, nullptr, nullptr, nullptr, 0.0, 0, Cc, PTd1);
  k_convt_bn<32,16,1,64,true,32,2><<<1024,256,0,stream>>>(
      Cc, w_d2, b_d2, PTd1, gt1, bet1, 1.0/65536.0, 512, A, PTd2);
  k_finalize2<16,1><<<1,256,0,stream>>>(PTd2, 1024, 1.0/262144.0, gt2, bet2, SS);
  k_convt_final<<<4096,256,0,stream>>>(A, w_d3, b_d3, SS, out);
}

// Round 13
// 337.112 us; speedup vs baseline: 1.0775x; 1.0775x over previous
//
#include <hip/hip_runtime.h>
#include <math.h>

typedef __bf16 bf16x8 __attribute__((ext_vector_type(8)));
typedef __bf16 bf16x4 __attribute__((ext_vector_type(4)));
typedef float  f32x16 __attribute__((ext_vector_type(16)));

static __device__ __forceinline__ f32x16 zero16() {
  f32x16 v;
  #pragma unroll
  for (int i = 0; i < 16; ++i) v[i] = 0.f;
  return v;
}
static __device__ __forceinline__ unsigned int bfbits(__bf16 b) {
  return (unsigned int)__builtin_bit_cast(unsigned short, b);
}
static __device__ __forceinline__ bf16x8 mk8(unsigned int a, unsigned int b,
                                             unsigned int c, unsigned int d) {
  uint4 t; t.x = a; t.y = b; t.z = c; t.w = d;
  return __builtin_bit_cast(bf16x8, t);
}

// ---------------- conv1: 1x1 stride2, 3->16, fused BN batch-stats partials ----------------
__global__ __launch_bounds__(256) void k_conv1(const float* __restrict__ x,
    const float* __restrict__ w, const float* __restrict__ b, float* __restrict__ y,
    float* __restrict__ partials) {
  int t = blockIdx.x*256 + threadIdx.x;        // 16*128*128 pixels
  int ox = t & 127, oy = (t >> 7) & 127, bb = t >> 14;
  const float* xp = x + ((size_t)((bb*256 + 2*oy)*256 + 2*ox))*3;
  float x0 = xp[0], x1 = xp[1], x2 = xp[2];
  float4 rg[4];
  float4* yp = (float4*)(y + (size_t)t*16);
  #pragma unroll
  for (int g = 0; g < 4; ++g) {
    float4 r;
    r.x = b[g*4+0] + x0*w[g*4+0] + x1*w[16+g*4+0] + x2*w[32+g*4+0];
    r.y = b[g*4+1] + x0*w[g*4+1] + x1*w[16+g*4+1] + x2*w[32+g*4+1];
    r.z = b[g*4+2] + x0*w[g*4+2] + x1*w[16+g*4+2] + x2*w[32+g*4+2];
    r.w = b[g*4+3] + x0*w[g*4+3] + x1*w[16+g*4+3] + x2*w[32+g*4+3];
    rg[g] = r;
    yp[g] = r;
  }
  float4 s4[4], q4[4];
  #pragma unroll
  for (int g=0; g<4; ++g) {
    s4[g] = rg[g];
    q4[g] = make_float4(rg[g].x*rg[g].x, rg[g].y*rg[g].y, rg[g].z*rg[g].z, rg[g].w*rg[g].w);
  }
  #pragma unroll
  for (int off=1; off<64; off<<=1) {
    #pragma unroll
    for (int g=0; g<4; ++g) {
      s4[g].x += __shfl_xor(s4[g].x, off); s4[g].y += __shfl_xor(s4[g].y, off);
      s4[g].z += __shfl_xor(s4[g].z, off); s4[g].w += __shfl_xor(s4[g].w, off);
      q4[g].x += __shfl_xor(q4[g].x, off); q4[g].y += __shfl_xor(q4[g].y, off);
      q4[g].z += __shfl_xor(q4[g].z, off); q4[g].w += __shfl_xor(q4[g].w, off);
    }
  }
  __shared__ float red[4][32];
  int wv = threadIdx.x >> 6, lane = threadIdx.x & 63;
  if (lane == 0) {
    #pragma unroll
    for (int g=0; g<4; ++g) {
      *(float4*)&red[wv][g*4]      = s4[g];
      *(float4*)&red[wv][16 + g*4] = q4[g];
    }
  }
  __syncthreads();
  if (threadIdx.x < 32)
    partials[(size_t)blockIdx.x*32 + threadIdx.x] =
      red[0][threadIdx.x]+red[1][threadIdx.x]+red[2][threadIdx.x]+red[3][threadIdx.x];
}

// ---------------- finalize: partials([blk][2*COUTT], blk%CSPLIT=chgroup) -> scale/shift ---
template<int C,int CSPLIT>
__global__ __launch_bounds__(256) void k_finalize2(const float* __restrict__ partials, int nblk,
    double inv_n, const float* __restrict__ g, const float* __restrict__ be, float* __restrict__ ss) {
  const int COUTT = C/CSPLIT;
  const int NSTAT = 2*C;
  const int PER = 256/NSTAT;
  __shared__ double red[256];
  int tid = threadIdx.x;
  int st = tid % NSTAT, sub = tid / NSTAT;
  int c = st % C, kind = st / C;
  int cq = c / COUTT, j = c % COUTT;
  int nb = nblk / CSPLIT;
  double acc = 0.0;
  #pragma unroll 4
  for (int i = sub; i < nb; i += PER) {
    int bq = cq + i*CSPLIT;
    acc += (double)partials[(size_t)bq*2*COUTT + kind*COUTT + j];
  }
  red[tid] = acc;
  __syncthreads();
  for (int off = PER>>1; off > 0; off >>= 1) {
    if (sub < off) red[tid] += red[tid + off*NSTAT];
    __syncthreads();
  }
  if (tid < C) {
    double mean = red[tid]*inv_n;
    double var  = red[C+tid]*inv_n - mean*mean;
    float scale = g[tid] * rsqrtf((float)var + 1e-3f);
    float shift = be[tid] - (float)mean*scale;
    ss[tid] = scale; ss[C+tid] = shift;
  }
}

// ---------------- forward 3x3 stride-2 SAME conv, fused input BN+ReLU + fused stats -----
template<int CIN,int COUT,int CSPLIT,int HIN,int HOUT,bool BN>
__global__ __launch_bounds__(256) void k_conv_bn(const float* __restrict__ in,
    const float* __restrict__ w, const float* __restrict__ bias,
    const float* __restrict__ ss, float* __restrict__ y, float* __restrict__ partials) {
  const int COUTT = COUT/CSPLIT;
  const int NW4 = COUTT/4;
  __shared__ float4 wlds[9*CIN*NW4];
  int bid = blockIdx.x;
  int cq  = bid % CSPLIT;
  int pxb = bid / CSPLIT;
  int c0  = cq*COUTT;
  for (int e = threadIdx.x; e < 9*CIN*NW4; e += 256) {
    int r = e / NW4, cg = e % NW4;
    wlds[e] = *(const float4*)(w + (size_t)r*COUT + c0 + cg*4);
  }
  __syncthreads();
  int t0 = pxb*256 + threadIdx.x;
  float4 acc[NW4];
  #pragma unroll
  for (int g=0; g<NW4; ++g) acc[g] = *(const float4*)(bias + c0 + g*4);
  int ox = t0 % HOUT, oy = (t0/HOUT) % HOUT, bb = t0/(HOUT*HOUT);
  #pragma unroll 1
  for (int dy=0; dy<3; ++dy) {
    #pragma unroll 1
    for (int dx=0; dx<3; ++dx) {
      int tap = dy*3+dx;
      int iy = 2*oy + dy, ix = 2*ox + dx;
      if (iy < HIN && ix < HIN) {
        const float* bp = in + ((size_t)(bb*HIN + iy)*HIN + ix)*CIN;
        #pragma unroll
        for (int ci4=0; ci4<CIN/4; ++ci4) {
          float4 v = *(const float4*)(bp + ci4*4);
          if (BN) {
            float4 sc = *(const float4*)(ss + ci4*4);
            float4 sh = *(const float4*)(ss + CIN + ci4*4);
            v.x = fmaxf(0.f, fmaf(v.x, sc.x, sh.x));
            v.y = fmaxf(0.f, fmaf(v.y, sc.y, sh.y));
            v.z = fmaxf(0.f, fmaf(v.z, sc.z, sh.z));
            v.w = fmaxf(0.f, fmaf(v.w, sc.w, sh.w));
          }
          float va[4] = {v.x, v.y, v.z, v.w};
          #pragma unroll
          for (int k=0;k<4;++k) {
            float vk = va[k];
            #pragma unroll
            for (int g=0; g<NW4; ++g) {
              float4 w4 = wlds[(tap*CIN + ci4*4 + k)*NW4 + g];
              acc[g].x = fmaf(vk, w4.x, acc[g].x);
              acc[g].y = fmaf(vk, w4.y, acc[g].y);
              acc[g].z = fmaf(vk, w4.z, acc[g].z);
              acc[g].w = fmaf(vk, w4.w, acc[g].w);
            }
          }
        }
      }
    }
  }
  float4* yp = (float4*)(y + (size_t)t0*COUT + c0);
  #pragma unroll
  for (int g=0;g<NW4;++g) yp[g] = acc[g];
  float4 s4[NW4], q4[NW4];
  #pragma unroll
  for (int g=0; g<NW4; ++g) {
    s4[g] = acc[g];
    q4[g] = make_float4(acc[g].x*acc[g].x, acc[g].y*acc[g].y,
                        acc[g].z*acc[g].z, acc[g].w*acc[g].w);
  }
  #pragma unroll
  for (int off=1; off<64; off<<=1) {
    #pragma unroll
    for (int g=0; g<NW4; ++g) {
      s4[g].x += __shfl_xor(s4[g].x, off); s4[g].y += __shfl_xor(s4[g].y, off);
      s4[g].z += __shfl_xor(s4[g].z, off); s4[g].w += __shfl_xor(s4[g].w, off);
      q4[g].x += __shfl_xor(q4[g].x, off); q4[g].y += __shfl_xor(q4[g].y, off);
      q4[g].z += __shfl_xor(q4[g].z, off); q4[g].w += __shfl_xor(q4[g].w, off);
    }
  }
  __shared__ float red[4][2*COUTT];
  int wv = threadIdx.x >> 6, lane = threadIdx.x & 63;
  if (lane == 0) {
    #pragma unroll
    for (int g=0; g<NW4; ++g) {
      *(float4*)&red[wv][g*4]         = s4[g];
      *(float4*)&red[wv][COUTT + g*4] = q4[g];
    }
  }
  __syncthreads();
  if (threadIdx.x < 2*COUTT)
    partials[(size_t)bid*2*COUTT + threadIdx.x] =
      red[0][threadIdx.x]+red[1][threadIdx.x]+red[2][threadIdx.x]+red[3][threadIdx.x];
}

// ================= memory module (MFMA 32x32x16, two-pass, u=exp stored bf16) ==========

__global__ __launch_bounds__(256) void k_prep_z(const float* __restrict__ y3,
    const float* __restrict__ ss,
    __bf16* __restrict__ ZH, __bf16* __restrict__ ZL,
    __bf16* __restrict__ Z2H, __bf16* __restrict__ Z2L) {
  int t = blockIdx.x*256 + threadIdx.x;   // handles 4 elems
  float4 v = ((const float4*)y3)[t];
  int c0 = (t*4) & 63;
  float4 sc = *(const float4*)(ss + c0);
  float4 sh = *(const float4*)(ss + 64 + c0);
  float vv[4];
  vv[0] = fmaxf(0.f, fmaf(v.x, sc.x, sh.x));
  vv[1] = fmaxf(0.f, fmaf(v.y, sc.y, sh.y));
  vv[2] = fmaxf(0.f, fmaf(v.z, sc.z, sh.z));
  vv[3] = fmaxf(0.f, fmaf(v.w, sc.w, sh.w));
  bf16x4 h, l, h2, l2;
  #pragma unroll
  for (int i=0;i<4;++i) {
    float f = vv[i];
    __bf16 hb = (__bf16)f;
    h[i] = hb; l[i] = (__bf16)(f - (float)hb);
    float q = f*f;
    __bf16 qb = (__bf16)q;
    h2[i] = qb; l2[i] = (__bf16)(q - (float)qb);
  }
  ((bf16x4*)ZH)[t] = h;  ((bf16x4*)ZL)[t] = l;
  ((bf16x4*)Z2H)[t] = h2; ((bf16x4*)Z2L)[t] = l2;
}

__global__ __launch_bounds__(256) void k_prep_m(const float* __restrict__ mem,
    __bf16* __restrict__ MH, __bf16* __restrict__ ML,
    __bf16* __restrict__ M2H, __bf16* __restrict__ M2L,
    __bf16* __restrict__ MHT) {
  int t = blockIdx.x*256 + threadIdx.x;   // 2048*16
  int n = t >> 4, c0 = (t & 15)*4;
  float4 v = make_float4(0.f,0.f,0.f,0.f);
  if (n < 2000) v = *(const float4*)(mem + (size_t)n*64 + c0);
  float vv[4] = {v.x, v.y, v.z, v.w};
  bf16x4 h, l, h2, l2;
  #pragma unroll
  for (int i=0;i<4;++i) {
    float f = vv[i];
    __bf16 hb = (__bf16)f;
    h[i] = hb; l[i] = (__bf16)(f - (float)hb);
    float q = f*f;
    __bf16 qb = (__bf16)q;
    h2[i] = qb; l2[i] = (__bf16)(q - (float)qb);
  }
  *(bf16x4*)(MH  + (size_t)n*64 + c0) = h;
  *(bf16x4*)(ML  + (size_t)n*64 + c0) = l;
  *(bf16x4*)(M2H + (size_t)n*64 + c0) = h2;
  *(bf16x4*)(M2L + (size_t)n*64 + c0) = l2;
  #pragma unroll
  for (int i=0;i<4;++i) {
    MHT[(size_t)(c0+i)*2048 + n] = h[i];
  }
}

// pass1: scores via MFMA; per-tile INDEPENDENT softmax partials; stores u=exp(s-tmax) bf16
// + per-tile max MT + chunk partials. 4-wave blocks.
// XCD-aware swizzle: all 16 chunks of one pbg land on the same XCD (round-robin dispatch,
// xcd = bid % 8) so shared z-fragments are fetched into ONE L2, not 4-8.
__global__ __launch_bounds__(256) void k_pass1(
    const __bf16* __restrict__ ZH, const __bf16* __restrict__ ZL,
    const __bf16* __restrict__ Z2H, const __bf16* __restrict__ Z2L,
    const __bf16* __restrict__ MH, const __bf16* __restrict__ ML,
    const __bf16* __restrict__ M2H, const __bf16* __restrict__ M2L,
    __bf16* __restrict__ U, float* __restrict__ MT,
    float* __restrict__ partM, float* __restrict__ partS) {
  int bid = blockIdx.x;
  int xcd = bid & 7;
  int j   = bid >> 3;                     // 0..255
  int pbg = xcd*16 + (j >> 4);            // 0..127 (16 pbgs per XCD)
  int chunk = j & 15;                     // 16 chunks, all on this XCD
  int wave = threadIdx.x >> 6, lane = threadIdx.x & 63;
  int p0 = pbg*128 + wave*32;
  int col = lane & 31, hi = lane >> 5;
  bf16x8 bzh[4], bzl[4], b2h[4], b2l[4];
  size_t zoff = (size_t)(p0 + col)*64 + hi*8;
  #pragma unroll
  for (int ks=0;ks<4;++ks) {
    bzh[ks] = *(const bf16x8*)(ZH  + zoff + ks*16);
    bzl[ks] = *(const bf16x8*)(ZL  + zoff + ks*16);
    b2h[ks] = *(const bf16x8*)(Z2H + zoff + ks*16);
    b2l[ks] = *(const bf16x8*)(Z2L + zoff + ks*16);
  }
  float tmaxv[4], ssumv[4];
  int nbase = chunk*128;
  #pragma unroll
  for (int t=0; t<4; ++t) {
    int n0 = nbase + t*32;
    size_t arow = (size_t)(n0 + col)*64 + hi*8;
    f32x16 num = zero16(), den = zero16();
    #pragma unroll
    for (int ks=0;ks<4;++ks) {
      bf16x8 amh = *(const bf16x8*)(MH + arow + ks*16);
      bf16x8 aml = *(const bf16x8*)(ML + arow + ks*16);
      num = __builtin_amdgcn_mfma_f32_32x32x16_bf16(amh, bzh[ks], num, 0,0,0);
      num = __builtin_amdgcn_mfma_f32_32x32x16_bf16(amh, bzl[ks], num, 0,0,0);
      num = __builtin_amdgcn_mfma_f32_32x32x16_bf16(aml, bzh[ks], num, 0,0,0);
      bf16x8 a2h = *(const bf16x8*)(M2H + arow + ks*16);
      bf16x8 a2l = *(const bf16x8*)(M2L + arow + ks*16);
      den = __builtin_amdgcn_mfma_f32_32x32x16_bf16(a2h, b2h[ks], den, 0,0,0);
      den = __builtin_amdgcn_mfma_f32_32x32x16_bf16(a2h, b2l[ks], den, 0,0,0);
      den = __builtin_amdgcn_mfma_f32_32x32x16_bf16(a2l, b2h[ks], den, 0,0,0);
    }
    bool maskt = (n0 + 32 > 2000);
    float sv[16];
    float tmax = -3.4e38f;
    #pragma unroll
    for (int r=0;r<16;++r) {
      float s = (num[r] + 1e-12f) * __builtin_amdgcn_rcpf(den[r] + 1e-12f);
      if (maskt) {
        int nn = n0 + (r&3) + 8*(r>>2) + 4*hi;
        if (nn >= 2000) s = -3.4e38f;
      }
      sv[r] = s;
      tmax = fmaxf(tmax, s);
    }
    float ssum = 0.f;
    unsigned int up[8];
    #pragma unroll
    for (int jj=0;jj<8;++jj) {
      float u0 = __expf(sv[2*jj]   - tmax);
      float u1 = __expf(sv[2*jj+1] - tmax);
      ssum += u0; ssum += u1;
      up[jj] = bfbits((__bf16)u0) | (bfbits((__bf16)u1) << 16);
    }
    size_t idx = (size_t)((chunk*4 + t)*16384 + p0 + col)*2 + hi;
    uint4 st0; st0.x = up[0]; st0.y = up[1]; st0.z = up[2]; st0.w = up[3];
    uint4 st1; st1.x = up[4]; st1.y = up[5]; st1.z = up[6]; st1.w = up[7];
    *(uint4*)(U + idx*16)     = st0;
    *(uint4*)(U + idx*16 + 8) = st1;
    MT[idx] = tmax;
    tmaxv[t] = tmax; ssumv[t] = ssum;
  }
  // combine 4 independent tiles, then the lane-halves
  float m = fmaxf(fmaxf(tmaxv[0], tmaxv[1]), fmaxf(tmaxv[2], tmaxv[3]));
  float S = ssumv[0]*__expf(tmaxv[0]-m) + ssumv[1]*__expf(tmaxv[1]-m)
          + ssumv[2]*__expf(tmaxv[2]-m) + ssumv[3]*__expf(tmaxv[3]-m);
  float mo = __shfl_xor(m, 32);
  float So = __shfl_xor(S, 32);
  float mf = fmaxf(m, mo);
  float Sf = S*__expf(m - mf) + So*__expf(mo - mf);
  if (lane < 32) {
    int p = p0 + col;
    partM[chunk*16384 + p] = mf;
    partS[chunk*16384 + p] = Sf;
  }
}

// pass2 (fused with zcomb): block = 4 waves x 32 p-cols; wave w covers n-tiles 16w..16w+15.
// r = u*exp(mt-CM) thresholded; zhat via MFMA (m-hi only); LDS-reduce 4 waves -> Gz fp32.
__global__ __launch_bounds__(256) void k_pass2(
    const __bf16* __restrict__ U, const float* __restrict__ MT,
    const __bf16* __restrict__ MHT,
    const float* __restrict__ partM, const float* __restrict__ partS,
    float* __restrict__ Gz) {
  __shared__ float zl[4][32][68];
  int pbg = blockIdx.x;                   // 512 p-groups of 32
  int wave = threadIdx.x >> 6, lane = threadIdx.x & 63;
  int p0 = pbg*32;
  int col = lane & 31, hi = lane >> 5;
  int p = p0 + col;
  float pmv[16];
  float Mp = -3.4e38f;
  #pragma unroll
  for (int c=0;c<16;++c) { pmv[c] = partM[c*16384 + p]; Mp = fmaxf(Mp, pmv[c]); }
  float Ssum = 0.f;
  #pragma unroll
  for (int c=0;c<16;++c) Ssum += partS[c*16384 + p] * __expf(pmv[c] - Mp);
  float CM  = Mp + __logf(Ssum);
  float thr = CM - 7.6009025f;     // + ln(1/2000)
  f32x16 za0 = zero16(), za1 = zero16();
  #pragma unroll 2
  for (int t=0; t<16; ++t) {
    int tg = wave*16 + t;
    int n0 = tg*32;
    size_t idx = (size_t)(tg*16384 + p)*2 + hi;
    uint4 a = *(const uint4*)(U + idx*16);
    uint4 b = *(const uint4*)(U + idx*16 + 8);
    float mt = MT[idx];
    float scale = __expf(mt - CM);
    float thru  = __expf(thr - mt);
    unsigned int ua[8] = {a.x,a.y,a.z,a.w,b.x,b.y,b.z,b.w};
    unsigned int qh[8];
    #pragma unroll
    for (int jj=0;jj<8;++jj) {
      float u0 = __builtin_bit_cast(float, ua[jj] << 16);
      float u1 = __builtin_bit_cast(float, ua[jj] & 0xffff0000u);
      float r0 = (u0 > thru) ? u0*scale : 0.f;
      float r1 = (u1 > thru) ? u1*scale : 0.f;
      qh[jj] = bfbits((__bf16)r0) | (bfbits((__bf16)r1) << 16);
    }
    unsigned int qhp[8];
    #pragma unroll
    for (int i=0;i<8;++i) qhp[i] = (unsigned int)__shfl_xor((int)qh[i], 32);
    bf16x8 f1h = hi ? mk8(qhp[2],qhp[3],qh[2],qh[3]) : mk8(qh[0],qh[1],qhp[0],qhp[1]);
    bf16x8 f2h = hi ? mk8(qhp[6],qhp[7],qh[6],qh[7]) : mk8(qh[4],qh[5],qhp[4],qhp[5]);
    #pragma unroll
    for (int kh=0; kh<2; ++kh) {
      bf16x8 fh = kh ? f2h : f1h;
      size_t bofs = (size_t)col*2048 + n0 + kh*16 + hi*8;
      bf16x8 bmh0 = *(const bf16x8*)(MHT + bofs);
      bf16x8 bmh1 = *(const bf16x8*)(MHT + bofs + (size_t)32*2048);
      za0 = __builtin_amdgcn_mfma_f32_32x32x16_bf16(fh, bmh0, za0, 0,0,0);
      za1 = __builtin_amdgcn_mfma_f32_32x32x16_bf16(fh, bmh1, za1, 0,0,0);
    }
  }
  // stash per-wave partials in LDS
  #pragma unroll
  for (int r=0;r<16;++r) {
    int prow = (r&3) + 8*(r>>2) + 4*hi;
    zl[wave][prow][col]      = za0[r];
    zl[wave][prow][col + 32] = za1[r];
  }
  __syncthreads();
  // reduce 4 waves and write Gz fp32: thread -> (p-local, 8 channels)
  int tp = threadIdx.x >> 3;
  int tc = (threadIdx.x & 7) * 8;
  float4 s0 = make_float4(0.f,0.f,0.f,0.f);
  float4 s1 = make_float4(0.f,0.f,0.f,0.f);
  #pragma unroll
  for (int w2=0; w2<4; ++w2) {
    float4 a0 = *(const float4*)&zl[w2][tp][tc];
    float4 a1 = *(const float4*)&zl[w2][tp][tc+4];
    s0.x += a0.x; s0.y += a0.y; s0.z += a0.z; s0.w += a0.w;
    s1.x += a1.x; s1.y += a1.y; s1.z += a1.z; s1.w += a1.w;
  }
  float* gp = Gz + (size_t)(p0 + tp)*64 + tc;
  *(float4*)gp       = s0;
  *(float4*)(gp + 4) = s1;
}

// ---------------- conv_transpose 3x3 stride2 SAME, parity-class blocks + fused stats ----
template<int CIN,int COUT,int CSPLIT,int HIN,bool BN>
__global__ __launch_bounds__(256) void k_convt_bn(const float* __restrict__ in,
    const float* __restrict__ w, const float* __restrict__ bias,
    const float* __restrict__ ss, float* __restrict__ y, float* __restrict__ partials) {
  const int COUTT = COUT/CSPLIT;
  const int HOUT = 2*HIN;
  __shared__ float4 wlds[4*COUTT*(CIN/4)];
  int bid = blockIdx.x;
  int cq = bid % CSPLIT; int rest = bid / CSPLIT;
  int cls = rest % 4;    int pxb = rest / 4;
  int pm = cls >> 1, pn = cls & 1;
  int c0 = cq*COUTT;
  int NTI = (pm == 0) ? 2 : 1;
  int NTJ = (pn == 0) ? 2 : 1;
  int NT = NTI*NTJ;
  for (int e = threadIdx.x; e < NT*COUTT*(CIN/4); e += 256) {
    int tl = e / (COUTT*(CIN/4));
    int rem = e % (COUTT*(CIN/4));
    int cc = rem / (CIN/4), ci4 = rem % (CIN/4);
    int ki = pm + 2*(tl / NTJ), kj = pn + 2*(tl % NTJ);
    wlds[e] = *(const float4*)(w + ((size_t)(ki*3+kj)*COUT + c0 + cc)*CIN + ci4*4);
  }
  __syncthreads();
  int t0 = pxb*256 + threadIdx.x;
  float acc[COUTT];
  #pragma unroll
  for (int cc=0;cc<COUTT;++cc) acc[cc] = bias[c0+cc];
  int nx = t0 % HIN, my = (t0/HIN) % HIN, bb = t0/(HIN*HIN);
  #pragma unroll 1
  for (int ti=0; ti<NTI; ++ti) {
    #pragma unroll 1
    for (int tj=0; tj<NTJ; ++tj) {
      int tl = ti*NTJ + tj;
      int i = my - ti, j = nx - tj;
      if (i >= 0 && j >= 0) {
        const float* bp = in + ((size_t)(bb*HIN + i)*HIN + j)*CIN;
        #pragma unroll
        for (int ci4=0; ci4<CIN/4; ++ci4) {
          float4 v = *(const float4*)(bp + ci4*4);
          if (BN) {
            float4 sc = *(const float4*)(ss + ci4*4);
            float4 sh = *(const float4*)(ss + CIN + ci4*4);
            v.x = fmaxf(0.f, fmaf(v.x, sc.x, sh.x));
            v.y = fmaxf(0.f, fmaf(v.y, sc.y, sh.y));
            v.z = fmaxf(0.f, fmaf(v.z, sc.z, sh.z));
            v.w = fmaxf(0.f, fmaf(v.w, sc.w, sh.w));
          }
          #pragma unroll
          for (int cc=0;cc<COUTT;++cc) {
            float4 w4 = wlds[(tl*COUTT + cc)*(CIN/4) + ci4];
            float a = acc[cc];
            a = fmaf(v.x, w4.x, a);
            a = fmaf(v.y, w4.y, a);
            a = fmaf(v.z, w4.z, a);
            a = fmaf(v.w, w4.w, a);
            acc[cc] = a;
          }
        }
      }
    }
  }
  int m = 2*my + pm, n = 2*nx + pn;
  float* yp = y + ((size_t)(bb*HOUT + m)*HOUT + n)*COUT + c0;
  #pragma unroll
  for (int g=0;g<COUTT/4;++g)
    ((float4*)yp)[g] = make_float4(acc[g*4], acc[g*4+1], acc[g*4+2], acc[g*4+3]);
  float s[COUTT], q[COUTT];
  #pragma unroll
  for (int cc=0;cc<COUTT;++cc) { s[cc] = acc[cc]; q[cc] = acc[cc]*acc[cc]; }
  #pragma unroll
  for (int off=1; off<64; off<<=1) {
    #pragma unroll
    for (int cc=0;cc<COUTT;++cc) {
      s[cc] += __shfl_xor(s[cc], off);
      q[cc] += __shfl_xor(q[cc], off);
    }
  }
  __shared__ float red[4][2*COUTT];
  int wv = threadIdx.x >> 6, lane = threadIdx.x & 63;
  if (lane == 0) {
    #pragma unroll
    for (int cc=0;cc<COUTT;++cc) { red[wv][cc] = s[cc]; red[wv][COUTT+cc] = q[cc]; }
  }
  __syncthreads();
  if (threadIdx.x < 2*COUTT)
    partials[(size_t)bid*2*COUTT + threadIdx.x] =
      red[0][threadIdx.x]+red[1][threadIdx.x]+red[2][threadIdx.x]+red[3][threadIdx.x];
}

// ---------------- final conv_transpose 16->3 + input BN+ReLU + clip ----------------
__global__ __launch_bounds__(256) void k_convt_final(const float* __restrict__ in,
    const float* __restrict__ w, const float* __restrict__ bias,
    const float* __restrict__ ss, float* __restrict__ out) {
  const int CIN=16, HIN=128, HOUT=256;
  __shared__ float4 wlds[4*3*4];     // [tap][c][ci4]
  int cls = blockIdx.x & 3;
  int pxb = blockIdx.x >> 2;
  int pm = cls >> 1, pn = cls & 1;
  int NTI = (pm == 0) ? 2 : 1;
  int NTJ = (pn == 0) ? 2 : 1;
  int NT = NTI*NTJ;
  if (threadIdx.x < NT*3*4) {
    int e = threadIdx.x;
    int tl = e / 12, rem = e % 12;
    int c = rem / 4, ci4 = rem % 4;
    int ki = pm + 2*(tl / NTJ), kj = pn + 2*(tl % NTJ);
    wlds[e] = *(const float4*)(w + ((size_t)(ki*3+kj)*3 + c)*CIN + ci4*4);
  }
  __syncthreads();
  int t = pxb*256 + threadIdx.x;
  int nx = t % HIN, my = (t/HIN) % HIN, bb = t/(HIN*HIN);
  float a0 = bias[0], a1 = bias[1], a2 = bias[2];
  #pragma unroll 1
  for (int ti=0; ti<NTI; ++ti) {
    #pragma unroll 1
    for (int tj=0; tj<NTJ; ++tj) {
      int tl = ti*NTJ + tj;
      int i = my - ti, j = nx - tj;
      if (i >= 0 && j >= 0) {
        const float* bp = in + ((size_t)(bb*HIN + i)*HIN + j)*CIN;
        #pragma unroll
        for (int ci4=0; ci4<4; ++ci4) {
          float4 v = *(const float4*)(bp + ci4*4);
          float4 sc = *(const float4*)(ss + ci4*4);
          float4 sh = *(const float4*)(ss + CIN + ci4*4);
          v.x = fmaxf(0.f, fmaf(v.x, sc.x, sh.x));
          v.y = fmaxf(0.f, fmaf(v.y, sc.y, sh.y));
          v.z = fmaxf(0.f, fmaf(v.z, sc.z, sh.z));
          v.w = fmaxf(0.f, fmaf(v.w, sc.w, sh.w));
          float4 w0 = wlds[(tl*3 + 0)*4 + ci4];
          float4 w1 = wlds[(tl*3 + 1)*4 + ci4];
          float4 w2 = wlds[(tl*3 + 2)*4 + ci4];
          a0 = fmaf(v.x, w0.x, a0); a0 = fmaf(v.y, w0.y, a0);
          a0 = fmaf(v.z, w0.z, a0); a0 = fmaf(v.w, w0.w, a0);
          a1 = fmaf(v.x, w1.x, a1); a1 = fmaf(v.y, w1.y, a1);
          a1 = fmaf(v.z, w1.z, a1); a1 = fmaf(v.w, w1.w, a1);
          a2 = fmaf(v.x, w2.x, a2); a2 = fmaf(v.y, w2.y, a2);
          a2 = fmaf(v.z, w2.z, a2); a2 = fmaf(v.w, w2.w, a2);
        }
      }
    }
  }
  int m = 2*my + pm, n = 2*nx + pn;
  float* op = out + ((size_t)(bb*HOUT + m)*HOUT + n)*3;
  op[0] = fminf(fmaxf(a0, 1e-12f), 1.0f);
  op[1] = fminf(fmaxf(a1, 1e-12f), 1.0f);
  op[2] = fminf(fmaxf(a2, 1e-12f), 1.0f);
}

extern "C" void kernel_launch(void* const* d_in, const int* in_sizes, int n_in,
                              void* d_out, int out_size, void* d_ws, size_t ws_size,
                              hipStream_t stream) {
  const float* x    = (const float*)d_in[0];
  const float* w_e1 = (const float*)d_in[1];
  const float* b_e1 = (const float*)d_in[2];
  const float* g1   = (const float*)d_in[3];
  const float* be1  = (const float*)d_in[4];
  const float* w_e2 = (const float*)d_in[5];
  const float* b_e2 = (const float*)d_in[6];
  const float* g2   = (const float*)d_in[7];
  const float* be2  = (const float*)d_in[8];
  const float* w_e3 = (const float*)d_in[9];
  const float* b_e3 = (const float*)d_in[10];
  const float* g3   = (const float*)d_in[11];
  const float* be3  = (const float*)d_in[12];
  const float* wmem = (const float*)d_in[13];
  const float* w_d1 = (const float*)d_in[14];
  const float* b_d1 = (const float*)d_in[15];
  const float* gt1  = (const float*)d_in[16];
  const float* bet1 = (const float*)d_in[17];
  const float* w_d2 = (const float*)d_in[18];
  const float* b_d2 = (const float*)d_in[19];
  const float* gt2  = (const float*)d_in[20];
  const float* bet2 = (const float*)d_in[21];
  const float* w_d3 = (const float*)d_in[22];
  const float* b_d3 = (const float*)d_in[23];
  float* out = (float*)d_out;

  float* ws = (float*)d_ws;
  // U (u=exp bf16, 64 tiles x 16384 p x 32): alive pass1->pass2 only.
  // A (y1/t2) and Cc (y2/t1) alias its head (live ranges disjoint from U's).
  __bf16* U  = (__bf16*)ws;              // 33,554,432 bf16 = 16,777,216 floats
  float* A   = ws;                       // 4,194,304 (alias: y1 enc / t2 dec)
  float* Cc  = ws + 4194304;             // 2,097,152 (alias: y2 enc / t1 dec)
  float* Gz  = ws + 16777216;            // 1,048,576 zhat
  float* E   = Gz + 1048576 + 8388608;   // 1,048,576 y3 raw
  float* bfbase = E + 1048576;
  __bf16* ZH  = (__bf16*)bfbase;                 // 16384*64 each
  __bf16* ZL  = ZH  + 16384*64;
  __bf16* Z2H = ZL  + 16384*64;
  __bf16* Z2L = Z2H + 16384*64;
  __bf16* MH  = Z2L + 16384*64;                  // 2048*64 each
  __bf16* ML  = MH  + 2048*64;
  __bf16* M2H = ML  + 2048*64;
  __bf16* M2L = M2H + 2048*64;
  __bf16* MHT = M2L + 2048*64;                   // 64*2048
  __bf16* MLT = MHT + 64*2048;                   // (unused)
  float* PT   = (float*)(MLT + 64*2048);         // 131072 BN partials
  float* SS   = PT + 131072;                     // 256
  float* PM   = SS + 256;                        // 262144 partM [16][16384]
  float* PS   = PM + 262144;                     // 262144 partS
  float* MT   = PS + 262144;                     // 2097152 per-tile max [64][16384][2]
  (void)ws_size; (void)in_sizes; (void)n_in; (void)out_size;

  // ---- encoder ----
  k_conv1<<<1024,256,0,stream>>>(x, w_e1, b_e1, A, PT);
  k_finalize2<16,1><<<1,256,0,stream>>>(PT, 1024, 1.0/262144.0, g1, be1, SS);
  k_conv_bn<16,32,2,128,64,true><<<512,256,0,stream>>>(A, w_e2, b_e2, SS, Cc, PT);
  k_finalize2<32,2><<<1,256,0,stream>>>(PT, 512, 1.0/65536.0, g2, be2, SS);
  k_conv_bn<32,64,8,64,32,true><<<512,256,0,stream>>>(Cc, w_e3, b_e3, SS, E, PT);
  k_finalize2<64,8><<<1,256,0,stream>>>(PT, 512, 1.0/16384.0, g3, be3, SS);
  // ---- memory addressing (MFMA two-pass; BN3+ReLU fused into prep_z) ----
  k_prep_m<<<128,256,0,stream>>>(wmem, MH, ML, M2H, M2L, MHT);
  k_prep_z<<<1024,256,0,stream>>>(E, SS, ZH, ZL, Z2H, Z2L);
  k_pass1<<<2048,256,0,stream>>>(ZH, ZL, Z2H, Z2L, MH, ML, M2H, M2L, U, MT, PM, PS);
  k_pass2<<<512,256,0,stream>>>(U, MT, MHT, PM, PS, Gz);
  // ---- decoder ----
  k_convt_bn<64,32,2,32,false><<<512,256,0,stream>>>(Gz, w_d1, b_d1, nullptr, Cc, PT);
  k_finalize2<32,2><<<1,256,0,stream>>>(PT, 512, 1.0/65536.0, gt1, bet1, SS);
  k_convt_bn<32,16,1,64,true><<<1024,256,0,stream>>>(Cc, w_d2, b_d2, SS, A, PT);
  k_finalize2<16,1><<<1,256,0,stream>>>(PT, 1024, 1.0/262144.0, gt2, bet2, SS);
  k_convt_final<<<4096,256,0,stream>>>(A, w_d3, b_d3, SS, out);
}

// Round 14
// 324.591 us; speedup vs baseline: 1.1191x; 1.0386x over previous
//
#include <hip/hip_runtime.h>
#include <math.h>

typedef __bf16 bf16x8 __attribute__((ext_vector_type(8)));
typedef __bf16 bf16x4 __attribute__((ext_vector_type(4)));
typedef float  f32x16 __attribute__((ext_vector_type(16)));

static __device__ __forceinline__ f32x16 zero16() {
  f32x16 v;
  #pragma unroll
  for (int i = 0; i < 16; ++i) v[i] = 0.f;
  return v;
}
static __device__ __forceinline__ unsigned int bfbits(__bf16 b) {
  return (unsigned int)__builtin_bit_cast(unsigned short, b);
}
static __device__ __forceinline__ bf16x8 mk8(unsigned int a, unsigned int b,
                                             unsigned int c, unsigned int d) {
  uint4 t; t.x = a; t.y = b; t.z = c; t.w = d;
  return __builtin_bit_cast(bf16x8, t);
}

// ---------------- conv1: 1x1 stride2, 3->16, fused BN batch-stats partials ----------------
__global__ __launch_bounds__(256) void k_conv1(const float* __restrict__ x,
    const float* __restrict__ w, const float* __restrict__ b, float* __restrict__ y,
    float* __restrict__ partials) {
  int t = blockIdx.x*256 + threadIdx.x;        // 16*128*128 pixels
  int ox = t & 127, oy = (t >> 7) & 127, bb = t >> 14;
  const float* xp = x + ((size_t)((bb*256 + 2*oy)*256 + 2*ox))*3;
  float x0 = xp[0], x1 = xp[1], x2 = xp[2];
  float4 rg[4];
  float4* yp = (float4*)(y + (size_t)t*16);
  #pragma unroll
  for (int g = 0; g < 4; ++g) {
    float4 r;
    r.x = b[g*4+0] + x0*w[g*4+0] + x1*w[16+g*4+0] + x2*w[32+g*4+0];
    r.y = b[g*4+1] + x0*w[g*4+1] + x1*w[16+g*4+1] + x2*w[32+g*4+1];
    r.z = b[g*4+2] + x0*w[g*4+2] + x1*w[16+g*4+2] + x2*w[32+g*4+2];
    r.w = b[g*4+3] + x0*w[g*4+3] + x1*w[16+g*4+3] + x2*w[32+g*4+3];
    rg[g] = r;
    yp[g] = r;
  }
  float4 s4[4], q4[4];
  #pragma unroll
  for (int g=0; g<4; ++g) {
    s4[g] = rg[g];
    q4[g] = make_float4(rg[g].x*rg[g].x, rg[g].y*rg[g].y, rg[g].z*rg[g].z, rg[g].w*rg[g].w);
  }
  #pragma unroll
  for (int off=1; off<64; off<<=1) {
    #pragma unroll
    for (int g=0; g<4; ++g) {
      s4[g].x += __shfl_xor(s4[g].x, off); s4[g].y += __shfl_xor(s4[g].y, off);
      s4[g].z += __shfl_xor(s4[g].z, off); s4[g].w += __shfl_xor(s4[g].w, off);
      q4[g].x += __shfl_xor(q4[g].x, off); q4[g].y += __shfl_xor(q4[g].y, off);
      q4[g].z += __shfl_xor(q4[g].z, off); q4[g].w += __shfl_xor(q4[g].w, off);
    }
  }
  __shared__ float red[4][32];
  int wv = threadIdx.x >> 6, lane = threadIdx.x & 63;
  if (lane == 0) {
    #pragma unroll
    for (int g=0; g<4; ++g) {
      *(float4*)&red[wv][g*4]      = s4[g];
      *(float4*)&red[wv][16 + g*4] = q4[g];
    }
  }
  __syncthreads();
  if (threadIdx.x < 32)
    partials[(size_t)blockIdx.x*32 + threadIdx.x] =
      red[0][threadIdx.x]+red[1][threadIdx.x]+red[2][threadIdx.x]+red[3][threadIdx.x];
}

// ---------------- finalize: partials([blk][2*COUTT], blk%CSPLIT=chgroup) -> scale/shift ---
template<int C,int CSPLIT>
__global__ __launch_bounds__(256) void k_finalize2(const float* __restrict__ partials, int nblk,
    double inv_n, const float* __restrict__ g, const float* __restrict__ be, float* __restrict__ ss) {
  const int COUTT = C/CSPLIT;
  const int NSTAT = 2*C;
  const int PER = 256/NSTAT;
  __shared__ double red[256];
  int tid = threadIdx.x;
  int st = tid % NSTAT, sub = tid / NSTAT;
  int c = st % C, kind = st / C;
  int cq = c / COUTT, j = c % COUTT;
  int nb = nblk / CSPLIT;
  double acc = 0.0;
  #pragma unroll 4
  for (int i = sub; i < nb; i += PER) {
    int bq = cq + i*CSPLIT;
    acc += (double)partials[(size_t)bq*2*COUTT + kind*COUTT + j];
  }
  red[tid] = acc;
  __syncthreads();
  for (int off = PER>>1; off > 0; off >>= 1) {
    if (sub < off) red[tid] += red[tid + off*NSTAT];
    __syncthreads();
  }
  if (tid < C) {
    double mean = red[tid]*inv_n;
    double var  = red[C+tid]*inv_n - mean*mean;
    float scale = g[tid] * rsqrtf((float)var + 1e-3f);
    float shift = be[tid] - (float)mean*scale;
    ss[tid] = scale; ss[C+tid] = shift;
  }
}

// ---------------- forward 3x3 stride-2 SAME conv, fused input BN+ReLU + fused stats -----
template<int CIN,int COUT,int CSPLIT,int HIN,int HOUT,bool BN>
__global__ __launch_bounds__(256) void k_conv_bn(const float* __restrict__ in,
    const float* __restrict__ w, const float* __restrict__ bias,
    const float* __restrict__ ss, float* __restrict__ y, float* __restrict__ partials) {
  const int COUTT = COUT/CSPLIT;
  const int NW4 = COUTT/4;
  __shared__ float4 wlds[9*CIN*NW4];
  int bid = blockIdx.x;
  int cq  = bid % CSPLIT;
  int pxb = bid / CSPLIT;
  int c0  = cq*COUTT;
  for (int e = threadIdx.x; e < 9*CIN*NW4; e += 256) {
    int r = e / NW4, cg = e % NW4;
    wlds[e] = *(const float4*)(w + (size_t)r*COUT + c0 + cg*4);
  }
  __syncthreads();
  int t0 = pxb*256 + threadIdx.x;
  float4 acc[NW4];
  #pragma unroll
  for (int g=0; g<NW4; ++g) acc[g] = *(const float4*)(bias + c0 + g*4);
  int ox = t0 % HOUT, oy = (t0/HOUT) % HOUT, bb = t0/(HOUT*HOUT);
  #pragma unroll 1
  for (int dy=0; dy<3; ++dy) {
    #pragma unroll 1
    for (int dx=0; dx<3; ++dx) {
      int tap = dy*3+dx;
      int iy = 2*oy + dy, ix = 2*ox + dx;
      if (iy < HIN && ix < HIN) {
        const float* bp = in + ((size_t)(bb*HIN + iy)*HIN + ix)*CIN;
        #pragma unroll
        for (int ci4=0; ci4<CIN/4; ++ci4) {
          float4 v = *(const float4*)(bp + ci4*4);
          if (BN) {
            float4 sc = *(const float4*)(ss + ci4*4);
            float4 sh = *(const float4*)(ss + CIN + ci4*4);
            v.x = fmaxf(0.f, fmaf(v.x, sc.x, sh.x));
            v.y = fmaxf(0.f, fmaf(v.y, sc.y, sh.y));
            v.z = fmaxf(0.f, fmaf(v.z, sc.z, sh.z));
            v.w = fmaxf(0.f, fmaf(v.w, sc.w, sh.w));
          }
          float va[4] = {v.x, v.y, v.z, v.w};
          #pragma unroll
          for (int k=0;k<4;++k) {
            float vk = va[k];
            #pragma unroll
            for (int g=0; g<NW4; ++g) {
              float4 w4 = wlds[(tap*CIN + ci4*4 + k)*NW4 + g];
              acc[g].x = fmaf(vk, w4.x, acc[g].x);
              acc[g].y = fmaf(vk, w4.y, acc[g].y);
              acc[g].z = fmaf(vk, w4.z, acc[g].z);
              acc[g].w = fmaf(vk, w4.w, acc[g].w);
            }
          }
        }
      }
    }
  }
  float4* yp = (float4*)(y + (size_t)t0*COUT + c0);
  #pragma unroll
  for (int g=0;g<NW4;++g) yp[g] = acc[g];
  float4 s4[NW4], q4[NW4];
  #pragma unroll
  for (int g=0; g<NW4; ++g) {
    s4[g] = acc[g];
    q4[g] = make_float4(acc[g].x*acc[g].x, acc[g].y*acc[g].y,
                        acc[g].z*acc[g].z, acc[g].w*acc[g].w);
  }
  #pragma unroll
  for (int off=1; off<64; off<<=1) {
    #pragma unroll
    for (int g=0; g<NW4; ++g) {
      s4[g].x += __shfl_xor(s4[g].x, off); s4[g].y += __shfl_xor(s4[g].y, off);
      s4[g].z += __shfl_xor(s4[g].z, off); s4[g].w += __shfl_xor(s4[g].w, off);
      q4[g].x += __shfl_xor(q4[g].x, off); q4[g].y += __shfl_xor(q4[g].y, off);
      q4[g].z += __shfl_xor(q4[g].z, off); q4[g].w += __shfl_xor(q4[g].w, off);
    }
  }
  __shared__ float red[4][2*COUTT];
  int wv = threadIdx.x >> 6, lane = threadIdx.x & 63;
  if (lane == 0) {
    #pragma unroll
    for (int g=0; g<NW4; ++g) {
      *(float4*)&red[wv][g*4]         = s4[g];
      *(float4*)&red[wv][COUTT + g*4] = q4[g];
    }
  }
  __syncthreads();
  if (threadIdx.x < 2*COUTT)
    partials[(size_t)bid*2*COUTT + threadIdx.x] =
      red[0][threadIdx.x]+red[1][threadIdx.x]+red[2][threadIdx.x]+red[3][threadIdx.x];
}

// ================= memory module (MFMA 32x32x16, two-pass, u=exp stored bf16) ==========

__global__ __launch_bounds__(256) void k_prep_z(const float* __restrict__ y3,
    const float* __restrict__ ss,
    __bf16* __restrict__ ZH, __bf16* __restrict__ ZL,
    __bf16* __restrict__ Z2H, __bf16* __restrict__ Z2L) {
  int t = blockIdx.x*256 + threadIdx.x;   // handles 4 elems
  float4 v = ((const float4*)y3)[t];
  int c0 = (t*4) & 63;
  float4 sc = *(const float4*)(ss + c0);
  float4 sh = *(const float4*)(ss + 64 + c0);
  float vv[4];
  vv[0] = fmaxf(0.f, fmaf(v.x, sc.x, sh.x));
  vv[1] = fmaxf(0.f, fmaf(v.y, sc.y, sh.y));
  vv[2] = fmaxf(0.f, fmaf(v.z, sc.z, sh.z));
  vv[3] = fmaxf(0.f, fmaf(v.w, sc.w, sh.w));
  bf16x4 h, l, h2, l2;
  #pragma unroll
  for (int i=0;i<4;++i) {
    float f = vv[i];
    __bf16 hb = (__bf16)f;
    h[i] = hb; l[i] = (__bf16)(f - (float)hb);
    float q = f*f;
    __bf16 qb = (__bf16)q;
    h2[i] = qb; l2[i] = (__bf16)(q - (float)qb);
  }
  ((bf16x4*)ZH)[t] = h;  ((bf16x4*)ZL)[t] = l;
  ((bf16x4*)Z2H)[t] = h2; ((bf16x4*)Z2L)[t] = l2;
}

// prep mem: writes MH/ML/M2H/M2L (CONTIGUOUS, stride 131072 bf16) + MHT transposed
__global__ __launch_bounds__(256) void k_prep_m(const float* __restrict__ mem,
    __bf16* __restrict__ MH, __bf16* __restrict__ ML,
    __bf16* __restrict__ M2H, __bf16* __restrict__ M2L,
    __bf16* __restrict__ MHT) {
  int t = blockIdx.x*256 + threadIdx.x;   // 2048*16
  int n = t >> 4, c0 = (t & 15)*4;
  float4 v = make_float4(0.f,0.f,0.f,0.f);
  if (n < 2000) v = *(const float4*)(mem + (size_t)n*64 + c0);
  float vv[4] = {v.x, v.y, v.z, v.w};
  bf16x4 h, l, h2, l2;
  #pragma unroll
  for (int i=0;i<4;++i) {
    float f = vv[i];
    __bf16 hb = (__bf16)f;
    h[i] = hb; l[i] = (__bf16)(f - (float)hb);
    float q = f*f;
    __bf16 qb = (__bf16)q;
    h2[i] = qb; l2[i] = (__bf16)(q - (float)qb);
  }
  *(bf16x4*)(MH  + (size_t)n*64 + c0) = h;
  *(bf16x4*)(ML  + (size_t)n*64 + c0) = l;
  *(bf16x4*)(M2H + (size_t)n*64 + c0) = h2;
  *(bf16x4*)(M2L + (size_t)n*64 + c0) = l2;
  #pragma unroll
  for (int i=0;i<4;++i) {
    MHT[(size_t)(c0+i)*2048 + n] = h[i];
  }
}

// pass1: scores via MFMA; M chunk staged in LDS (slot-major, conflict-free reads);
// per-tile independent softmax partials; u=exp(s-tmax) bf16 + MT + chunk partials.
// XCD swizzle: all 16 chunks of one pbg on the same XCD.
// LDS layout: [arr(4)][slot(8)][row(128)][8 bf16]; arr = {MH,ML,M2H,M2L} (contiguous
// in global, stride 131072); slot = 16B index within a 64-ch row (slot = hi + 2*ks).
__global__ __launch_bounds__(256) void k_pass1(
    const __bf16* __restrict__ MH,
    const __bf16* __restrict__ ZH, const __bf16* __restrict__ ZL,
    const __bf16* __restrict__ Z2H, const __bf16* __restrict__ Z2L,
    __bf16* __restrict__ U, float* __restrict__ MT,
    float* __restrict__ partM, float* __restrict__ partS) {
  __shared__ __bf16 mlds[32768];          // 64 KB
  int bid = blockIdx.x;
  int xcd = bid & 7;
  int j   = bid >> 3;
  int pbg = xcd*16 + (j >> 4);
  int chunk = j & 15;
  int wave = threadIdx.x >> 6, lane = threadIdx.x & 63;
  int p0 = pbg*128 + wave*32;
  int col = lane & 31, hi = lane >> 5;
  int nbase = chunk*128;
  // z-frags (issue before staging so global loads overlap)
  bf16x8 bzh[4], bzl[4], b2h[4], b2l[4];
  size_t zoff = (size_t)(p0 + col)*64 + hi*8;
  #pragma unroll
  for (int ks=0;ks<4;++ks) {
    bzh[ks] = *(const bf16x8*)(ZH  + zoff + ks*16);
    bzl[ks] = *(const bf16x8*)(ZL  + zoff + ks*16);
    b2h[ks] = *(const bf16x8*)(Z2H + zoff + ks*16);
    b2l[ks] = *(const bf16x8*)(Z2L + zoff + ks*16);
  }
  // stage M chunk: 4 arrays x 128 rows x 64 ch bf16 = 4096 x 16B
  for (int i = threadIdx.x; i < 4096; i += 256) {
    int arr = i >> 10, rem = i & 1023;
    int row = rem >> 3, slot = rem & 7;
    uint4 v = *(const uint4*)(MH + (size_t)arr*131072 + (size_t)(nbase+row)*64 + slot*8);
    *(uint4*)(mlds + arr*8192 + slot*1024 + row*8) = v;
  }
  __syncthreads();
  float tmaxv[4], ssumv[4];
  #pragma unroll
  for (int t=0; t<4; ++t) {
    int n0 = nbase + t*32;
    int rowb = (t*32 + col)*8;
    f32x16 num = zero16(), den = zero16();
    #pragma unroll
    for (int ks=0;ks<4;++ks) {
      int so = (hi + 2*ks)*1024 + rowb;
      bf16x8 amh = *(const bf16x8*)(mlds + so);
      bf16x8 aml = *(const bf16x8*)(mlds + 8192 + so);
      num = __builtin_amdgcn_mfma_f32_32x32x16_bf16(amh, bzh[ks], num, 0,0,0);
      num = __builtin_amdgcn_mfma_f32_32x32x16_bf16(amh, bzl[ks], num, 0,0,0);
      num = __builtin_amdgcn_mfma_f32_32x32x16_bf16(aml, bzh[ks], num, 0,0,0);
      bf16x8 a2h = *(const bf16x8*)(mlds + 16384 + so);
      bf16x8 a2l = *(const bf16x8*)(mlds + 24576 + so);
      den = __builtin_amdgcn_mfma_f32_32x32x16_bf16(a2h, b2h[ks], den, 0,0,0);
      den = __builtin_amdgcn_mfma_f32_32x32x16_bf16(a2h, b2l[ks], den, 0,0,0);
      den = __builtin_amdgcn_mfma_f32_32x32x16_bf16(a2l, b2h[ks], den, 0,0,0);
    }
    bool maskt = (n0 + 32 > 2000);
    float sv[16];
    float tmax = -3.4e38f;
    #pragma unroll
    for (int r=0;r<16;++r) {
      float s = (num[r] + 1e-12f) * __builtin_amdgcn_rcpf(den[r] + 1e-12f);
      if (maskt) {
        int nn = n0 + (r&3) + 8*(r>>2) + 4*hi;
        if (nn >= 2000) s = -3.4e38f;
      }
      sv[r] = s;
      tmax = fmaxf(tmax, s);
    }
    float ssum = 0.f;
    unsigned int up[8];
    #pragma unroll
    for (int jj=0;jj<8;++jj) {
      float u0 = __expf(sv[2*jj]   - tmax);
      float u1 = __expf(sv[2*jj+1] - tmax);
      ssum += u0; ssum += u1;
      up[jj] = bfbits((__bf16)u0) | (bfbits((__bf16)u1) << 16);
    }
    size_t idx = (size_t)((chunk*4 + t)*16384 + p0 + col)*2 + hi;
    uint4 st0; st0.x = up[0]; st0.y = up[1]; st0.z = up[2]; st0.w = up[3];
    uint4 st1; st1.x = up[4]; st1.y = up[5]; st1.z = up[6]; st1.w = up[7];
    *(uint4*)(U + idx*16)     = st0;
    *(uint4*)(U + idx*16 + 8) = st1;
    MT[idx] = tmax;
    tmaxv[t] = tmax; ssumv[t] = ssum;
  }
  // combine 4 independent tiles, then the lane-halves
  float m = fmaxf(fmaxf(tmaxv[0], tmaxv[1]), fmaxf(tmaxv[2], tmaxv[3]));
  float S = ssumv[0]*__expf(tmaxv[0]-m) + ssumv[1]*__expf(tmaxv[1]-m)
          + ssumv[2]*__expf(tmaxv[2]-m) + ssumv[3]*__expf(tmaxv[3]-m);
  float mo = __shfl_xor(m, 32);
  float So = __shfl_xor(S, 32);
  float mf = fmaxf(m, mo);
  float Sf = S*__expf(m - mf) + So*__expf(mo - mf);
  if (lane < 32) {
    int p = p0 + col;
    partM[chunk*16384 + p] = mf;
    partS[chunk*16384 + p] = Sf;
  }
}

// pass2 (fused with zcomb): block = 4 waves x 32 p-cols; wave w covers n-tiles 16w..16w+15.
// r = u*exp(mt-CM) thresholded; zhat via MFMA (m-hi only); LDS-reduce 4 waves -> Gz fp32.
__global__ __launch_bounds__(256) void k_pass2(
    const __bf16* __restrict__ U, const float* __restrict__ MT,
    const __bf16* __restrict__ MHT,
    const float* __restrict__ partM, const float* __restrict__ partS,
    float* __restrict__ Gz) {
  __shared__ float zl[4][32][68];
  int pbg = blockIdx.x;                   // 512 p-groups of 32
  int wave = threadIdx.x >> 6, lane = threadIdx.x & 63;
  int p0 = pbg*32;
  int col = lane & 31, hi = lane >> 5;
  int p = p0 + col;
  float pmv[16];
  float Mp = -3.4e38f;
  #pragma unroll
  for (int c=0;c<16;++c) { pmv[c] = partM[c*16384 + p]; Mp = fmaxf(Mp, pmv[c]); }
  float Ssum = 0.f;
  #pragma unroll
  for (int c=0;c<16;++c) Ssum += partS[c*16384 + p] * __expf(pmv[c] - Mp);
  float CM  = Mp + __logf(Ssum);
  float thr = CM - 7.6009025f;     // + ln(1/2000)
  f32x16 za0 = zero16(), za1 = zero16();
  #pragma unroll 2
  for (int t=0; t<16; ++t) {
    int tg = wave*16 + t;
    int n0 = tg*32;
    size_t idx = (size_t)(tg*16384 + p)*2 + hi;
    uint4 a = *(const uint4*)(U + idx*16);
    uint4 b = *(const uint4*)(U + idx*16 + 8);
    float mt = MT[idx];
    float scale = __expf(mt - CM);
    float thru  = __expf(thr - mt);
    unsigned int ua[8] = {a.x,a.y,a.z,a.w,b.x,b.y,b.z,b.w};
    unsigned int qh[8];
    #pragma unroll
    for (int jj=0;jj<8;++jj) {
      float u0 = __builtin_bit_cast(float, ua[jj] << 16);
      float u1 = __builtin_bit_cast(float, ua[jj] & 0xffff0000u);
      float r0 = (u0 > thru) ? u0*scale : 0.f;
      float r1 = (u1 > thru) ? u1*scale : 0.f;
      qh[jj] = bfbits((__bf16)r0) | (bfbits((__bf16)r1) << 16);
    }
    unsigned int qhp[8];
    #pragma unroll
    for (int i=0;i<8;++i) qhp[i] = (unsigned int)__shfl_xor((int)qh[i], 32);
    bf16x8 f1h = hi ? mk8(qhp[2],qhp[3],qh[2],qh[3]) : mk8(qh[0],qh[1],qhp[0],qhp[1]);
    bf16x8 f2h = hi ? mk8(qhp[6],qhp[7],qh[6],qh[7]) : mk8(qh[4],qh[5],qhp[4],qhp[5]);
    #pragma unroll
    for (int kh=0; kh<2; ++kh) {
      bf16x8 fh = kh ? f2h : f1h;
      size_t bofs = (size_t)col*2048 + n0 + kh*16 + hi*8;
      bf16x8 bmh0 = *(const bf16x8*)(MHT + bofs);
      bf16x8 bmh1 = *(const bf16x8*)(MHT + bofs + (size_t)32*2048);
      za0 = __builtin_amdgcn_mfma_f32_32x32x16_bf16(fh, bmh0, za0, 0,0,0);
      za1 = __builtin_amdgcn_mfma_f32_32x32x16_bf16(fh, bmh1, za1, 0,0,0);
    }
  }
  // stash per-wave partials in LDS
  #pragma unroll
  for (int r=0;r<16;++r) {
    int prow = (r&3) + 8*(r>>2) + 4*hi;
    zl[wave][prow][col]      = za0[r];
    zl[wave][prow][col + 32] = za1[r];
  }
  __syncthreads();
  // reduce 4 waves and write Gz fp32: thread -> (p-local, 8 channels)
  int tp = threadIdx.x >> 3;
  int tc = (threadIdx.x & 7) * 8;
  float4 s0 = make_float4(0.f,0.f,0.f,0.f);
  float4 s1 = make_float4(0.f,0.f,0.f,0.f);
  #pragma unroll
  for (int w2=0; w2<4; ++w2) {
    float4 a0 = *(const float4*)&zl[w2][tp][tc];
    float4 a1 = *(const float4*)&zl[w2][tp][tc+4];
    s0.x += a0.x; s0.y += a0.y; s0.z += a0.z; s0.w += a0.w;
    s1.x += a1.x; s1.y += a1.y; s1.z += a1.z; s1.w += a1.w;
  }
  float* gp = Gz + (size_t)(p0 + tp)*64 + tc;
  *(float4*)gp       = s0;
  *(float4*)(gp + 4) = s1;
}

// ---------------- conv_transpose 3x3 stride2 SAME, parity-class blocks + fused stats ----
template<int CIN,int COUT,int CSPLIT,int HIN,bool BN>
__global__ __launch_bounds__(256) void k_convt_bn(const float* __restrict__ in,
    const float* __restrict__ w, const float* __restrict__ bias,
    const float* __restrict__ ss, float* __restrict__ y, float* __restrict__ partials) {
  const int COUTT = COUT/CSPLIT;
  const int HOUT = 2*HIN;
  __shared__ float4 wlds[4*COUTT*(CIN/4)];
  int bid = blockIdx.x;
  int cq = bid % CSPLIT; int rest = bid / CSPLIT;
  int cls = rest % 4;    int pxb = rest / 4;
  int pm = cls >> 1, pn = cls & 1;
  int c0 = cq*COUTT;
  int NTI = (pm == 0) ? 2 : 1;
  int NTJ = (pn == 0) ? 2 : 1;
  int NT = NTI*NTJ;
  for (int e = threadIdx.x; e < NT*COUTT*(CIN/4); e += 256) {
    int tl = e / (COUTT*(CIN/4));
    int rem = e % (COUTT*(CIN/4));
    int cc = rem / (CIN/4), ci4 = rem % (CIN/4);
    int ki = pm + 2*(tl / NTJ), kj = pn + 2*(tl % NTJ);
    wlds[e] = *(const float4*)(w + ((size_t)(ki*3+kj)*COUT + c0 + cc)*CIN + ci4*4);
  }
  __syncthreads();
  int t0 = pxb*256 + threadIdx.x;
  float acc[COUTT];
  #pragma unroll
  for (int cc=0;cc<COUTT;++cc) acc[cc] = bias[c0+cc];
  int nx = t0 % HIN, my = (t0/HIN) % HIN, bb = t0/(HIN*HIN);
  #pragma unroll 1
  for (int ti=0; ti<NTI; ++ti) {
    #pragma unroll 1
    for (int tj=0; tj<NTJ; ++tj) {
      int tl = ti*NTJ + tj;
      int i = my - ti, j = nx - tj;
      if (i >= 0 && j >= 0) {
        const float* bp = in + ((size_t)(bb*HIN + i)*HIN + j)*CIN;
        #pragma unroll
        for (int ci4=0; ci4<CIN/4; ++ci4) {
          float4 v = *(const float4*)(bp + ci4*4);
          if (BN) {
            float4 sc = *(const float4*)(ss + ci4*4);
            float4 sh = *(const float4*)(ss + CIN + ci4*4);
            v.x = fmaxf(0.f, fmaf(v.x, sc.x, sh.x));
            v.y = fmaxf(0.f, fmaf(v.y, sc.y, sh.y));
            v.z = fmaxf(0.f, fmaf(v.z, sc.z, sh.z));
            v.w = fmaxf(0.f, fmaf(v.w, sc.w, sh.w));
          }
          #pragma unroll
          for (int cc=0;cc<COUTT;++cc) {
            float4 w4 = wlds[(tl*COUTT + cc)*(CIN/4) + ci4];
            float a = acc[cc];
            a = fmaf(v.x, w4.x, a);
            a = fmaf(v.y, w4.y, a);
            a = fmaf(v.z, w4.z, a);
            a = fmaf(v.w, w4.w, a);
            acc[cc] = a;
          }
        }
      }
    }
  }
  int m = 2*my + pm, n = 2*nx + pn;
  float* yp = y + ((size_t)(bb*HOUT + m)*HOUT + n)*COUT + c0;
  #pragma unroll
  for (int g=0;g<COUTT/4;++g)
    ((float4*)yp)[g] = make_float4(acc[g*4], acc[g*4+1], acc[g*4+2], acc[g*4+3]);
  float s[COUTT], q[COUTT];
  #pragma unroll
  for (int cc=0;cc<COUTT;++cc) { s[cc] = acc[cc]; q[cc] = acc[cc]*acc[cc]; }
  #pragma unroll
  for (int off=1; off<64; off<<=1) {
    #pragma unroll
    for (int cc=0;cc<COUTT;++cc) {
      s[cc] += __shfl_xor(s[cc], off);
      q[cc] += __shfl_xor(q[cc], off);
    }
  }
  __shared__ float red[4][2*COUTT];
  int wv = threadIdx.x >> 6, lane = threadIdx.x & 63;
  if (lane == 0) {
    #pragma unroll
    for (int cc=0;cc<COUTT;++cc) { red[wv][cc] = s[cc]; red[wv][COUTT+cc] = q[cc]; }
  }
  __syncthreads();
  if (threadIdx.x < 2*COUTT)
    partials[(size_t)bid*2*COUTT + threadIdx.x] =
      red[0][threadIdx.x]+red[1][threadIdx.x]+red[2][threadIdx.x]+red[3][threadIdx.x];
}

// ---------------- final conv_transpose 16->3 + input BN+ReLU + clip ----------------
__global__ __launch_bounds__(256) void k_convt_final(const float* __restrict__ in,
    const float* __restrict__ w, const float* __restrict__ bias,
    const float* __restrict__ ss, float* __restrict__ out) {
  const int CIN=16, HIN=128, HOUT=256;
  __shared__ float4 wlds[4*3*4];     // [tap][c][ci4]
  int cls = blockIdx.x & 3;
  int pxb = blockIdx.x >> 2;
  int pm = cls >> 1, pn = cls & 1;
  int NTI = (pm == 0) ? 2 : 1;
  int NTJ = (pn == 0) ? 2 : 1;
  int NT = NTI*NTJ;
  if (threadIdx.x < NT*3*4) {
    int e = threadIdx.x;
    int tl = e / 12, rem = e % 12;
    int c = rem / 4, ci4 = rem % 4;
    int ki = pm + 2*(tl / NTJ), kj = pn + 2*(tl % NTJ);
    wlds[e] = *(const float4*)(w + ((size_t)(ki*3+kj)*3 + c)*CIN + ci4*4);
  }
  __syncthreads();
  int t = pxb*256 + threadIdx.x;
  int nx = t % HIN, my = (t/HIN) % HIN, bb = t/(HIN*HIN);
  float a0 = bias[0], a1 = bias[1], a2 = bias[2];
  #pragma unroll 1
  for (int ti=0; ti<NTI; ++ti) {
    #pragma unroll 1
    for (int tj=0; tj<NTJ; ++tj) {
      int tl = ti*NTJ + tj;
      int i = my - ti, j = nx - tj;
      if (i >= 0 && j >= 0) {
        const float* bp = in + ((size_t)(bb*HIN + i)*HIN + j)*CIN;
        #pragma unroll
        for (int ci4=0; ci4<4; ++ci4) {
          float4 v = *(const float4*)(bp + ci4*4);
          float4 sc = *(const float4*)(ss + ci4*4);
          float4 sh = *(const float4*)(ss + CIN + ci4*4);
          v.x = fmaxf(0.f, fmaf(v.x, sc.x, sh.x));
          v.y = fmaxf(0.f, fmaf(v.y, sc.y, sh.y));
          v.z = fmaxf(0.f, fmaf(v.z, sc.z, sh.z));
          v.w = fmaxf(0.f, fmaf(v.w, sc.w, sh.w));
          float4 w0 = wlds[(tl*3 + 0)*4 + ci4];
          float4 w1 = wlds[(tl*3 + 1)*4 + ci4];
          float4 w2 = wlds[(tl*3 + 2)*4 + ci4];
          a0 = fmaf(v.x, w0.x, a0); a0 = fmaf(v.y, w0.y, a0);
          a0 = fmaf(v.z, w0.z, a0); a0 = fmaf(v.w, w0.w, a0);
          a1 = fmaf(v.x, w1.x, a1); a1 = fmaf(v.y, w1.y, a1);
          a1 = fmaf(v.z, w1.z, a1); a1 = fmaf(v.w, w1.w, a1);
          a2 = fmaf(v.x, w2.x, a2); a2 = fmaf(v.y, w2.y, a2);
          a2 = fmaf(v.z, w2.z, a2); a2 = fmaf(v.w, w2.w, a2);
        }
      }
    }
  }
  int m = 2*my + pm, n = 2*nx + pn;
  float* op = out + ((size_t)(bb*HOUT + m)*HOUT + n)*3;
  op[0] = fminf(fmaxf(a0, 1e-12f), 1.0f);
  op[1] = fminf(fmaxf(a1, 1e-12f), 1.0f);
  op[2] = fminf(fmaxf(a2, 1e-12f), 1.0f);
}

extern "C" void kernel_launch(void* const* d_in, const int* in_sizes, int n_in,
                              void* d_out, int out_size, void* d_ws, size_t ws_size,
                              hipStream_t stream) {
  const float* x    = (const float*)d_in[0];
  const float* w_e1 = (const float*)d_in[1];
  const float* b_e1 = (const float*)d_in[2];
  const float* g1   = (const float*)d_in[3];
  const float* be1  = (const float*)d_in[4];
  const float* w_e2 = (const float*)d_in[5];
  const float* b_e2 = (const float*)d_in[6];
  const float* g2   = (const float*)d_in[7];
  const float* be2  = (const float*)d_in[8];
  const float* w_e3 = (const float*)d_in[9];
  const float* b_e3 = (const float*)d_in[10];
  const float* g3   = (const float*)d_in[11];
  const float* be3  = (const float*)d_in[12];
  const float* wmem = (const float*)d_in[13];
  const float* w_d1 = (const float*)d_in[14];
  const float* b_d1 = (const float*)d_in[15];
  const float* gt1  = (const float*)d_in[16];
  const float* bet1 = (const float*)d_in[17];
  const float* w_d2 = (const float*)d_in[18];
  const float* b_d2 = (const float*)d_in[19];
  const float* gt2  = (const float*)d_in[20];
  const float* bet2 = (const float*)d_in[21];
  const float* w_d3 = (const float*)d_in[22];
  const float* b_d3 = (const float*)d_in[23];
  float* out = (float*)d_out;

  float* ws = (float*)d_ws;
  // U (u=exp bf16, 64 tiles x 16384 p x 32): alive pass1->pass2 only.
  // A (y1/t2) and Cc (y2/t1) alias its head (live ranges disjoint from U's).
  __bf16* U  = (__bf16*)ws;              // 33,554,432 bf16 = 16,777,216 floats
  float* A   = ws;                       // 4,194,304 (alias: y1 enc / t2 dec)
  float* Cc  = ws + 4194304;             // 2,097,152 (alias: y2 enc / t1 dec)
  float* Gz  = ws + 16777216;            // 1,048,576 zhat
  float* E   = Gz + 1048576 + 8388608;   // 1,048,576 y3 raw
  float* bfbase = E + 1048576;
  __bf16* ZH  = (__bf16*)bfbase;                 // 16384*64 each
  __bf16* ZL  = ZH  + 16384*64;
  __bf16* Z2H = ZL  + 16384*64;
  __bf16* Z2L = Z2H + 16384*64;
  __bf16* MH  = Z2L + 16384*64;                  // 2048*64 each, MH/ML/M2H/M2L CONTIGUOUS
  __bf16* ML  = MH  + 2048*64;
  __bf16* M2H = ML  + 2048*64;
  __bf16* M2L = M2H + 2048*64;
  __bf16* MHT = M2L + 2048*64;                   // 64*2048
  __bf16* MLT = MHT + 64*2048;                   // (unused)
  float* PT   = (float*)(MLT + 64*2048);         // 131072 BN partials
  float* SS   = PT + 131072;                     // 256
  float* PM   = SS + 256;                        // 262144 partM [16][16384]
  float* PS   = PM + 262144;                     // 262144 partS
  float* MT   = PS + 262144;                     // 2097152 per-tile max [64][16384][2]
  (void)ws_size; (void)in_sizes; (void)n_in; (void)out_size;

  // ---- encoder ----
  k_conv1<<<1024,256,0,stream>>>(x, w_e1, b_e1, A, PT);
  k_finalize2<16,1><<<1,256,0,stream>>>(PT, 1024, 1.0/262144.0, g1, be1, SS);
  k_conv_bn<16,32,2,128,64,true><<<512,256,0,stream>>>(A, w_e2, b_e2, SS, Cc, PT);
  k_finalize2<32,2><<<1,256,0,stream>>>(PT, 512, 1.0/65536.0, g2, be2, SS);
  k_conv_bn<32,64,8,64,32,true><<<512,256,0,stream>>>(Cc, w_e3, b_e3, SS, E, PT);
  k_finalize2<64,8><<<1,256,0,stream>>>(PT, 512, 1.0/16384.0, g3, be3, SS);
  // ---- memory addressing (MFMA two-pass; BN3+ReLU fused into prep_z) ----
  k_prep_m<<<128,256,0,stream>>>(wmem, MH, ML, M2H, M2L, MHT);
  k_prep_z<<<1024,256,0,stream>>>(E, SS, ZH, ZL, Z2H, Z2L);
  k_pass1<<<2048,256,0,stream>>>(MH, ZH, ZL, Z2H, Z2L, U, MT, PM, PS);
  k_pass2<<<512,256,0,stream>>>(U, MT, MHT, PM, PS, Gz);
  // ---- decoder ----
  k_convt_bn<64,32,2,32,false><<<512,256,0,stream>>>(Gz, w_d1, b_d1, nullptr, Cc, PT);
  k_finalize2<32,2><<<1,256,0,stream>>>(PT, 512, 1.0/65536.0, gt1, bet1, SS);
  k_convt_bn<32,16,1,64,true><<<1024,256,0,stream>>>(Cc, w_d2, b_d2, SS, A, PT);
  k_finalize2<16,1><<<1,256,0,stream>>>(PT, 1024, 1.0/262144.0, gt2, bet2, SS);
  k_convt_final<<<4096,256,0,stream>>>(A, w_d3, b_d3, SS, out);
}

// Round 15
// 320.793 us; speedup vs baseline: 1.1324x; 1.0118x over previous
//
#include <hip/hip_runtime.h>
#include <math.h>

typedef __bf16 bf16x8 __attribute__((ext_vector_type(8)));
typedef __bf16 bf16x4 __attribute__((ext_vector_type(4)));
typedef float  f32x16 __attribute__((ext_vector_type(16)));

static __device__ __forceinline__ f32x16 zero16() {
  f32x16 v;
  #pragma unroll
  for (int i = 0; i < 16; ++i) v[i] = 0.f;
  return v;
}
static __device__ __forceinline__ unsigned int bfbits(__bf16 b) {
  return (unsigned int)__builtin_bit_cast(unsigned short, b);
}
static __device__ __forceinline__ bf16x8 mk8(unsigned int a, unsigned int b,
                                             unsigned int c, unsigned int d) {
  uint4 t; t.x = a; t.y = b; t.z = c; t.w = d;
  return __builtin_bit_cast(bf16x8, t);
}

// ---------------- conv1: 1x1 stride2, 3->16, fused BN batch-stats partials ----------------
__global__ __launch_bounds__(256) void k_conv1(const float* __restrict__ x,
    const float* __restrict__ w, const float* __restrict__ b, float* __restrict__ y,
    float* __restrict__ partials) {
  int t = blockIdx.x*256 + threadIdx.x;        // 16*128*128 pixels
  int ox = t & 127, oy = (t >> 7) & 127, bb = t >> 14;
  const float* xp = x + ((size_t)((bb*256 + 2*oy)*256 + 2*ox))*3;
  float x0 = xp[0], x1 = xp[1], x2 = xp[2];
  float4 rg[4];
  float4* yp = (float4*)(y + (size_t)t*16);
  #pragma unroll
  for (int g = 0; g < 4; ++g) {
    float4 r;
    r.x = b[g*4+0] + x0*w[g*4+0] + x1*w[16+g*4+0] + x2*w[32+g*4+0];
    r.y = b[g*4+1] + x0*w[g*4+1] + x1*w[16+g*4+1] + x2*w[32+g*4+1];
    r.z = b[g*4+2] + x0*w[g*4+2] + x1*w[16+g*4+2] + x2*w[32+g*4+2];
    r.w = b[g*4+3] + x0*w[g*4+3] + x1*w[16+g*4+3] + x2*w[32+g*4+3];
    rg[g] = r;
    yp[g] = r;
  }
  float4 s4[4], q4[4];
  #pragma unroll
  for (int g=0; g<4; ++g) {
    s4[g] = rg[g];
    q4[g] = make_float4(rg[g].x*rg[g].x, rg[g].y*rg[g].y, rg[g].z*rg[g].z, rg[g].w*rg[g].w);
  }
  #pragma unroll
  for (int off=1; off<64; off<<=1) {
    #pragma unroll
    for (int g=0; g<4; ++g) {
      s4[g].x += __shfl_xor(s4[g].x, off); s4[g].y += __shfl_xor(s4[g].y, off);
      s4[g].z += __shfl_xor(s4[g].z, off); s4[g].w += __shfl_xor(s4[g].w, off);
      q4[g].x += __shfl_xor(q4[g].x, off); q4[g].y += __shfl_xor(q4[g].y, off);
      q4[g].z += __shfl_xor(q4[g].z, off); q4[g].w += __shfl_xor(q4[g].w, off);
    }
  }
  __shared__ float red[4][32];
  int wv = threadIdx.x >> 6, lane = threadIdx.x & 63;
  if (lane == 0) {
    #pragma unroll
    for (int g=0; g<4; ++g) {
      *(float4*)&red[wv][g*4]      = s4[g];
      *(float4*)&red[wv][16 + g*4] = q4[g];
    }
  }
  __syncthreads();
  if (threadIdx.x < 32)
    partials[(size_t)blockIdx.x*32 + threadIdx.x] =
      red[0][threadIdx.x]+red[1][threadIdx.x]+red[2][threadIdx.x]+red[3][threadIdx.x];
}

// ---------------- finalize: partials([blk][2*COUTT], blk%CSPLIT=chgroup) -> scale/shift ---
template<int C,int CSPLIT>
__global__ __launch_bounds__(256) void k_finalize2(const float* __restrict__ partials, int nblk,
    double inv_n, const float* __restrict__ g, const float* __restrict__ be, float* __restrict__ ss) {
  const int COUTT = C/CSPLIT;
  const int NSTAT = 2*C;
  const int PER = 256/NSTAT;
  __shared__ double red[256];
  int tid = threadIdx.x;
  int st = tid % NSTAT, sub = tid / NSTAT;
  int c = st % C, kind = st / C;
  int cq = c / COUTT, j = c % COUTT;
  int nb = nblk / CSPLIT;
  double acc = 0.0;
  #pragma unroll 4
  for (int i = sub; i < nb; i += PER) {
    int bq = cq + i*CSPLIT;
    acc += (double)partials[(size_t)bq*2*COUTT + kind*COUTT + j];
  }
  red[tid] = acc;
  __syncthreads();
  for (int off = PER>>1; off > 0; off >>= 1) {
    if (sub < off) red[tid] += red[tid + off*NSTAT];
    __syncthreads();
  }
  if (tid < C) {
    double mean = red[tid]*inv_n;
    double var  = red[C+tid]*inv_n - mean*mean;
    float scale = g[tid] * rsqrtf((float)var + 1e-3f);
    float shift = be[tid] - (float)mean*scale;
    ss[tid] = scale; ss[C+tid] = shift;
  }
}

// ---------------- forward 3x3 stride-2 SAME conv, fused input BN+ReLU + fused stats -----
template<int CIN,int COUT,int CSPLIT,int HIN,int HOUT,bool BN>
__global__ __launch_bounds__(256) void k_conv_bn(const float* __restrict__ in,
    const float* __restrict__ w, const float* __restrict__ bias,
    const float* __restrict__ ss, float* __restrict__ y, float* __restrict__ partials) {
  const int COUTT = COUT/CSPLIT;
  const int NW4 = COUTT/4;
  __shared__ float4 wlds[9*CIN*NW4];
  int bid = blockIdx.x;
  int cq  = bid % CSPLIT;
  int pxb = bid / CSPLIT;
  int c0  = cq*COUTT;
  for (int e = threadIdx.x; e < 9*CIN*NW4; e += 256) {
    int r = e / NW4, cg = e % NW4;
    wlds[e] = *(const float4*)(w + (size_t)r*COUT + c0 + cg*4);
  }
  __syncthreads();
  int t0 = pxb*256 + threadIdx.x;
  float4 acc[NW4];
  #pragma unroll
  for (int g=0; g<NW4; ++g) acc[g] = *(const float4*)(bias + c0 + g*4);
  int ox = t0 % HOUT, oy = (t0/HOUT) % HOUT, bb = t0/(HOUT*HOUT);
  #pragma unroll 1
  for (int dy=0; dy<3; ++dy) {
    #pragma unroll 1
    for (int dx=0; dx<3; ++dx) {
      int tap = dy*3+dx;
      int iy = 2*oy + dy, ix = 2*ox + dx;
      if (iy < HIN && ix < HIN) {
        const float* bp = in + ((size_t)(bb*HIN + iy)*HIN + ix)*CIN;
        #pragma unroll
        for (int ci4=0; ci4<CIN/4; ++ci4) {
          float4 v = *(const float4*)(bp + ci4*4);
          if (BN) {
            float4 sc = *(const float4*)(ss + ci4*4);
            float4 sh = *(const float4*)(ss + CIN + ci4*4);
            v.x = fmaxf(0.f, fmaf(v.x, sc.x, sh.x));
            v.y = fmaxf(0.f, fmaf(v.y, sc.y, sh.y));
            v.z = fmaxf(0.f, fmaf(v.z, sc.z, sh.z));
            v.w = fmaxf(0.f, fmaf(v.w, sc.w, sh.w));
          }
          float va[4] = {v.x, v.y, v.z, v.w};
          #pragma unroll
          for (int k=0;k<4;++k) {
            float vk = va[k];
            #pragma unroll
            for (int g=0; g<NW4; ++g) {
              float4 w4 = wlds[(tap*CIN + ci4*4 + k)*NW4 + g];
              acc[g].x = fmaf(vk, w4.x, acc[g].x);
              acc[g].y = fmaf(vk, w4.y, acc[g].y);
              acc[g].z = fmaf(vk, w4.z, acc[g].z);
              acc[g].w = fmaf(vk, w4.w, acc[g].w);
            }
          }
        }
      }
    }
  }
  float4* yp = (float4*)(y + (size_t)t0*COUT + c0);
  #pragma unroll
  for (int g=0;g<NW4;++g) yp[g] = acc[g];
  float4 s4[NW4], q4[NW4];
  #pragma unroll
  for (int g=0; g<NW4; ++g) {
    s4[g] = acc[g];
    q4[g] = make_float4(acc[g].x*acc[g].x, acc[g].y*acc[g].y,
                        acc[g].z*acc[g].z, acc[g].w*acc[g].w);
  }
  #pragma unroll
  for (int off=1; off<64; off<<=1) {
    #pragma unroll
    for (int g=0; g<NW4; ++g) {
      s4[g].x += __shfl_xor(s4[g].x, off); s4[g].y += __shfl_xor(s4[g].y, off);
      s4[g].z += __shfl_xor(s4[g].z, off); s4[g].w += __shfl_xor(s4[g].w, off);
      q4[g].x += __shfl_xor(q4[g].x, off); q4[g].y += __shfl_xor(q4[g].y, off);
      q4[g].z += __shfl_xor(q4[g].z, off); q4[g].w += __shfl_xor(q4[g].w, off);
    }
  }
  __shared__ float red[4][2*COUTT];
  int wv = threadIdx.x >> 6, lane = threadIdx.x & 63;
  if (lane == 0) {
    #pragma unroll
    for (int g=0; g<NW4; ++g) {
      *(float4*)&red[wv][g*4]         = s4[g];
      *(float4*)&red[wv][COUTT + g*4] = q4[g];
    }
  }
  __syncthreads();
  if (threadIdx.x < 2*COUTT)
    partials[(size_t)bid*2*COUTT + threadIdx.x] =
      red[0][threadIdx.x]+red[1][threadIdx.x]+red[2][threadIdx.x]+red[3][threadIdx.x];
}

// ================= memory module (MFMA 32x32x16, two-pass, u=exp stored bf16) ==========

// fused prep: blocks [0,128) pack mem (+transpose); blocks [128,1152) BN3+ReLU + pack z
__global__ __launch_bounds__(256) void k_prep_mz(const float* __restrict__ mem,
    const float* __restrict__ y3, const float* __restrict__ ss,
    __bf16* __restrict__ MH, __bf16* __restrict__ ML,
    __bf16* __restrict__ M2H, __bf16* __restrict__ M2L, __bf16* __restrict__ MHT,
    __bf16* __restrict__ ZH, __bf16* __restrict__ ZL,
    __bf16* __restrict__ Z2H, __bf16* __restrict__ Z2L) {
  if (blockIdx.x < 128) {
    int t = blockIdx.x*256 + threadIdx.x;   // 2048*16
    int n = t >> 4, c0 = (t & 15)*4;
    float4 v = make_float4(0.f,0.f,0.f,0.f);
    if (n < 2000) v = *(const float4*)(mem + (size_t)n*64 + c0);
    float vv[4] = {v.x, v.y, v.z, v.w};
    bf16x4 h, l, h2, l2;
    #pragma unroll
    for (int i=0;i<4;++i) {
      float f = vv[i];
      __bf16 hb = (__bf16)f;
      h[i] = hb; l[i] = (__bf16)(f - (float)hb);
      float q = f*f;
      __bf16 qb = (__bf16)q;
      h2[i] = qb; l2[i] = (__bf16)(q - (float)qb);
    }
    *(bf16x4*)(MH  + (size_t)n*64 + c0) = h;
    *(bf16x4*)(ML  + (size_t)n*64 + c0) = l;
    *(bf16x4*)(M2H + (size_t)n*64 + c0) = h2;
    *(bf16x4*)(M2L + (size_t)n*64 + c0) = l2;
    #pragma unroll
    for (int i=0;i<4;++i) MHT[(size_t)(c0+i)*2048 + n] = h[i];
  } else {
    int t = (blockIdx.x - 128)*256 + threadIdx.x;   // handles 4 elems
    float4 v = ((const float4*)y3)[t];
    int c0 = (t*4) & 63;
    float4 sc = *(const float4*)(ss + c0);
    float4 sh = *(const float4*)(ss + 64 + c0);
    float vv[4];
    vv[0] = fmaxf(0.f, fmaf(v.x, sc.x, sh.x));
    vv[1] = fmaxf(0.f, fmaf(v.y, sc.y, sh.y));
    vv[2] = fmaxf(0.f, fmaf(v.z, sc.z, sh.z));
    vv[3] = fmaxf(0.f, fmaf(v.w, sc.w, sh.w));
    bf16x4 h, l, h2, l2;
    #pragma unroll
    for (int i=0;i<4;++i) {
      float f = vv[i];
      __bf16 hb = (__bf16)f;
      h[i] = hb; l[i] = (__bf16)(f - (float)hb);
      float q = f*f;
      __bf16 qb = (__bf16)q;
      h2[i] = qb; l2[i] = (__bf16)(q - (float)qb);
    }
    ((bf16x4*)ZH)[t] = h;  ((bf16x4*)ZL)[t] = l;
    ((bf16x4*)Z2H)[t] = h2; ((bf16x4*)Z2L)[t] = l2;
  }
}

// pass1: scores via MFMA; 64-row M half-chunk staged in LDS (32 KB); 32 chunks x 2 tiles.
// XCD swizzle: all 32 chunks of one pbg on the same XCD. partM/partS: [32][16384].
// LDS layout: [arr(4)][slot(8)][row(64)][8 bf16].
__global__ __launch_bounds__(256) void k_pass1(
    const __bf16* __restrict__ MH,
    const __bf16* __restrict__ ZH, const __bf16* __restrict__ ZL,
    const __bf16* __restrict__ Z2H, const __bf16* __restrict__ Z2L,
    __bf16* __restrict__ U, float* __restrict__ MT,
    float* __restrict__ partM, float* __restrict__ partS) {
  __shared__ __bf16 mlds[16384];          // 32 KB
  int bid = blockIdx.x;
  int xcd = bid & 7;
  int j   = bid >> 3;                     // 0..511
  int pbg = xcd*16 + (j >> 5);            // 0..127
  int chunk = j & 31;                     // 32 chunks of 64 n
  int wave = threadIdx.x >> 6, lane = threadIdx.x & 63;
  int p0 = pbg*128 + wave*32;
  int col = lane & 31, hi = lane >> 5;
  int nbase = chunk*64;
  // z-frags (issue before staging so global loads overlap)
  bf16x8 bzh[4], bzl[4], b2h[4], b2l[4];
  size_t zoff = (size_t)(p0 + col)*64 + hi*8;
  #pragma unroll
  for (int ks=0;ks<4;++ks) {
    bzh[ks] = *(const bf16x8*)(ZH  + zoff + ks*16);
    bzl[ks] = *(const bf16x8*)(ZL  + zoff + ks*16);
    b2h[ks] = *(const bf16x8*)(Z2H + zoff + ks*16);
    b2l[ks] = *(const bf16x8*)(Z2L + zoff + ks*16);
  }
  // stage M half-chunk: 4 arrays x 64 rows x 64 ch bf16 = 2048 x 16B
  for (int i = threadIdx.x; i < 2048; i += 256) {
    int arr = i >> 9, rem = i & 511;
    int row = rem >> 3, slot = rem & 7;
    uint4 v = *(const uint4*)(MH + (size_t)arr*131072 + (size_t)(nbase+row)*64 + slot*8);
    *(uint4*)(mlds + arr*4096 + slot*512 + row*8) = v;
  }
  __syncthreads();
  float tmaxv[2], ssumv[2];
  #pragma unroll
  for (int t=0; t<2; ++t) {
    int n0 = nbase + t*32;
    int rowb = (t*32 + col)*8;
    f32x16 num = zero16(), den = zero16();
    #pragma unroll
    for (int ks=0;ks<4;++ks) {
      int so = (hi + 2*ks)*512 + rowb;
      bf16x8 amh = *(const bf16x8*)(mlds + so);
      bf16x8 aml = *(const bf16x8*)(mlds + 4096 + so);
      num = __builtin_amdgcn_mfma_f32_32x32x16_bf16(amh, bzh[ks], num, 0,0,0);
      num = __builtin_amdgcn_mfma_f32_32x32x16_bf16(amh, bzl[ks], num, 0,0,0);
      num = __builtin_amdgcn_mfma_f32_32x32x16_bf16(aml, bzh[ks], num, 0,0,0);
      bf16x8 a2h = *(const bf16x8*)(mlds + 8192 + so);
      bf16x8 a2l = *(const bf16x8*)(mlds + 12288 + so);
      den = __builtin_amdgcn_mfma_f32_32x32x16_bf16(a2h, b2h[ks], den, 0,0,0);
      den = __builtin_amdgcn_mfma_f32_32x32x16_bf16(a2h, b2l[ks], den, 0,0,0);
      den = __builtin_amdgcn_mfma_f32_32x32x16_bf16(a2l, b2h[ks], den, 0,0,0);
    }
    bool maskt = (n0 + 32 > 2000);
    float sv[16];
    float tmax = -3.4e38f;
    #pragma unroll
    for (int r=0;r<16;++r) {
      float s = (num[r] + 1e-12f) * __builtin_amdgcn_rcpf(den[r] + 1e-12f);
      if (maskt) {
        int nn = n0 + (r&3) + 8*(r>>2) + 4*hi;
        if (nn >= 2000) s = -3.4e38f;
      }
      sv[r] = s;
      tmax = fmaxf(tmax, s);
    }
    float ssum = 0.f;
    unsigned int up[8];
    #pragma unroll
    for (int jj=0;jj<8;++jj) {
      float u0 = __expf(sv[2*jj]   - tmax);
      float u1 = __expf(sv[2*jj+1] - tmax);
      ssum += u0; ssum += u1;
      up[jj] = bfbits((__bf16)u0) | (bfbits((__bf16)u1) << 16);
    }
    size_t idx = (size_t)((chunk*2 + t)*16384 + p0 + col)*2 + hi;
    uint4 st0; st0.x = up[0]; st0.y = up[1]; st0.z = up[2]; st0.w = up[3];
    uint4 st1; st1.x = up[4]; st1.y = up[5]; st1.z = up[6]; st1.w = up[7];
    *(uint4*)(U + idx*16)     = st0;
    *(uint4*)(U + idx*16 + 8) = st1;
    MT[idx] = tmax;
    tmaxv[t] = tmax; ssumv[t] = ssum;
  }
  // combine 2 independent tiles, then the lane-halves
  float m = fmaxf(tmaxv[0], tmaxv[1]);
  float S = ssumv[0]*__expf(tmaxv[0]-m) + ssumv[1]*__expf(tmaxv[1]-m);
  float mo = __shfl_xor(m, 32);
  float So = __shfl_xor(S, 32);
  float mf = fmaxf(m, mo);
  float Sf = S*__expf(m - mf) + So*__expf(mo - mf);
  if (lane < 32) {
    int p = p0 + col;
    partM[chunk*16384 + p] = mf;
    partS[chunk*16384 + p] = Sf;
  }
}

// pass2 (fused with zcomb): block = 4 waves x 32 p-cols; wave w covers n-tiles 16w..16w+15.
// r = u*exp(mt-CM) thresholded; zhat via MFMA (m-hi only); LDS-reduce 4 waves -> Gz fp32.
__global__ __launch_bounds__(256) void k_pass2(
    const __bf16* __restrict__ U, const float* __restrict__ MT,
    const __bf16* __restrict__ MHT,
    const float* __restrict__ partM, const float* __restrict__ partS,
    float* __restrict__ Gz) {
  __shared__ float zl[4][32][68];
  int pbg = blockIdx.x;                   // 512 p-groups of 32
  int wave = threadIdx.x >> 6, lane = threadIdx.x & 63;
  int p0 = pbg*32;
  int col = lane & 31, hi = lane >> 5;
  int p = p0 + col;
  float Mp = -3.4e38f;
  #pragma unroll
  for (int c=0;c<32;++c) Mp = fmaxf(Mp, partM[c*16384 + p]);
  float Ssum = 0.f;
  #pragma unroll
  for (int c=0;c<32;++c) Ssum += partS[c*16384 + p] * __expf(partM[c*16384 + p] - Mp);
  float CM  = Mp + __logf(Ssum);
  float thr = CM - 7.6009025f;     // + ln(1/2000)
  f32x16 za0 = zero16(), za1 = zero16();
  #pragma unroll 2
  for (int t=0; t<16; ++t) {
    int tg = wave*16 + t;
    int n0 = tg*32;
    size_t idx = (size_t)(tg*16384 + p)*2 + hi;
    uint4 a = *(const uint4*)(U + idx*16);
    uint4 b = *(const uint4*)(U + idx*16 + 8);
    float mt = MT[idx];
    float scale = __expf(mt - CM);
    float thru  = __expf(thr - mt);
    unsigned int ua[8] = {a.x,a.y,a.z,a.w,b.x,b.y,b.z,b.w};
    unsigned int qh[8];
    #pragma unroll
    for (int jj=0;jj<8;++jj) {
      float u0 = __builtin_bit_cast(float, ua[jj] << 16);
      float u1 = __builtin_bit_cast(float, ua[jj] & 0xffff0000u);
      float r0 = (u0 > thru) ? u0*scale : 0.f;
      float r1 = (u1 > thru) ? u1*scale : 0.f;
      qh[jj] = bfbits((__bf16)r0) | (bfbits((__bf16)r1) << 16);
    }
    unsigned int qhp[8];
    #pragma unroll
    for (int i=0;i<8;++i) qhp[i] = (unsigned int)__shfl_xor((int)qh[i], 32);
    bf16x8 f1h = hi ? mk8(qhp[2],qhp[3],qh[2],qh[3]) : mk8(qh[0],qh[1],qhp[0],qhp[1]);
    bf16x8 f2h = hi ? mk8(qhp[6],qhp[7],qh[6],qh[7]) : mk8(qh[4],qh[5],qhp[4],qhp[5]);
    #pragma unroll
    for (int kh=0; kh<2; ++kh) {
      bf16x8 fh = kh ? f2h : f1h;
      size_t bofs = (size_t)col*2048 + n0 + kh*16 + hi*8;
      bf16x8 bmh0 = *(const bf16x8*)(MHT + bofs);
      bf16x8 bmh1 = *(const bf16x8*)(MHT + bofs + (size_t)32*2048);
      za0 = __builtin_amdgcn_mfma_f32_32x32x16_bf16(fh, bmh0, za0, 0,0,0);
      za1 = __builtin_amdgcn_mfma_f32_32x32x16_bf16(fh, bmh1, za1, 0,0,0);
    }
  }
  // stash per-wave partials in LDS
  #pragma unroll
  for (int r=0;r<16;++r) {
    int prow = (r&3) + 8*(r>>2) + 4*hi;
    zl[wave][prow][col]      = za0[r];
    zl[wave][prow][col + 32] = za1[r];
  }
  __syncthreads();
  // reduce 4 waves and write Gz fp32: thread -> (p-local, 8 channels)
  int tp = threadIdx.x >> 3;
  int tc = (threadIdx.x & 7) * 8;
  float4 s0 = make_float4(0.f,0.f,0.f,0.f);
  float4 s1 = make_float4(0.f,0.f,0.f,0.f);
  #pragma unroll
  for (int w2=0; w2<4; ++w2) {
    float4 a0 = *(const float4*)&zl[w2][tp][tc];
    float4 a1 = *(const float4*)&zl[w2][tp][tc+4];
    s0.x += a0.x; s0.y += a0.y; s0.z += a0.z; s0.w += a0.w;
    s1.x += a1.x; s1.y += a1.y; s1.z += a1.z; s1.w += a1.w;
  }
  float* gp = Gz + (size_t)(p0 + tp)*64 + tc;
  *(float4*)gp       = s0;
  *(float4*)(gp + 4) = s1;
}

// ---------------- conv_transpose 3x3 stride2 SAME, parity-class blocks + fused stats ----
template<int CIN,int COUT,int CSPLIT,int HIN,bool BN>
__global__ __launch_bounds__(256) void k_convt_bn(const float* __restrict__ in,
    const float* __restrict__ w, const float* __restrict__ bias,
    const float* __restrict__ ss, float* __restrict__ y, float* __restrict__ partials) {
  const int COUTT = COUT/CSPLIT;
  const int HOUT = 2*HIN;
  __shared__ float4 wlds[4*COUTT*(CIN/4)];
  int bid = blockIdx.x;
  int cq = bid % CSPLIT; int rest = bid / CSPLIT;
  int cls = rest % 4;    int pxb = rest / 4;
  int pm = cls >> 1, pn = cls & 1;
  int c0 = cq*COUTT;
  int NTI = (pm == 0) ? 2 : 1;
  int NTJ = (pn == 0) ? 2 : 1;
  int NT = NTI*NTJ;
  for (int e = threadIdx.x; e < NT*COUTT*(CIN/4); e += 256) {
    int tl = e / (COUTT*(CIN/4));
    int rem = e % (COUTT*(CIN/4));
    int cc = rem / (CIN/4), ci4 = rem % (CIN/4);
    int ki = pm + 2*(tl / NTJ), kj = pn + 2*(tl % NTJ);
    wlds[e] = *(const float4*)(w + ((size_t)(ki*3+kj)*COUT + c0 + cc)*CIN + ci4*4);
  }
  __syncthreads();
  int t0 = pxb*256 + threadIdx.x;
  float acc[COUTT];
  #pragma unroll
  for (int cc=0;cc<COUTT;++cc) acc[cc] = bias[c0+cc];
  int nx = t0 % HIN, my = (t0/HIN) % HIN, bb = t0/(HIN*HIN);
  #pragma unroll 1
  for (int ti=0; ti<NTI; ++ti) {
    #pragma unroll 1
    for (int tj=0; tj<NTJ; ++tj) {
      int tl = ti*NTJ + tj;
      int i = my - ti, j = nx - tj;
      if (i >= 0 && j >= 0) {
        const float* bp = in + ((size_t)(bb*HIN + i)*HIN + j)*CIN;
        #pragma unroll
        for (int ci4=0; ci4<CIN/4; ++ci4) {
          float4 v = *(const float4*)(bp + ci4*4);
          if (BN) {
            float4 sc = *(const float4*)(ss + ci4*4);
            float4 sh = *(const float4*)(ss + CIN + ci4*4);
            v.x = fmaxf(0.f, fmaf(v.x, sc.x, sh.x));
            v.y = fmaxf(0.f, fmaf(v.y, sc.y, sh.y));
            v.z = fmaxf(0.f, fmaf(v.z, sc.z, sh.z));
            v.w = fmaxf(0.f, fmaf(v.w, sc.w, sh.w));
          }
          #pragma unroll
          for (int cc=0;cc<COUTT;++cc) {
            float4 w4 = wlds[(tl*COUTT + cc)*(CIN/4) + ci4];
            float a = acc[cc];
            a = fmaf(v.x, w4.x, a);
            a = fmaf(v.y, w4.y, a);
            a = fmaf(v.z, w4.z, a);
            a = fmaf(v.w, w4.w, a);
            acc[cc] = a;
          }
        }
      }
    }
  }
  int m = 2*my + pm, n = 2*nx + pn;
  float* yp = y + ((size_t)(bb*HOUT + m)*HOUT + n)*COUT + c0;
  #pragma unroll
  for (int g=0;g<COUTT/4;++g)
    ((float4*)yp)[g] = make_float4(acc[g*4], acc[g*4+1], acc[g*4+2], acc[g*4+3]);
  float s[COUTT], q[COUTT];
  #pragma unroll
  for (int cc=0;cc<COUTT;++cc) { s[cc] = acc[cc]; q[cc] = acc[cc]*acc[cc]; }
  #pragma unroll
  for (int off=1; off<64; off<<=1) {
    #pragma unroll
    for (int cc=0;cc<COUTT;++cc) {
      s[cc] += __shfl_xor(s[cc], off);
      q[cc] += __shfl_xor(q[cc], off);
    }
  }
  __shared__ float red[4][2*COUTT];
  int wv = threadIdx.x >> 6, lane = threadIdx.x & 63;
  if (lane == 0) {
    #pragma unroll
    for (int cc=0;cc<COUTT;++cc) { red[wv][cc] = s[cc]; red[wv][COUTT+cc] = q[cc]; }
  }
  __syncthreads();
  if (threadIdx.x < 2*COUTT)
    partials[(size_t)bid*2*COUTT + threadIdx.x] =
      red[0][threadIdx.x]+red[1][threadIdx.x]+red[2][threadIdx.x]+red[3][threadIdx.x];
}

// ---------------- final conv_transpose 16->3 + input BN+ReLU + clip ----------------
__global__ __launch_bounds__(256) void k_convt_final(const float* __restrict__ in,
    const float* __restrict__ w, const float* __restrict__ bias,
    const float* __restrict__ ss, float* __restrict__ out) {
  const int CIN=16, HIN=128, HOUT=256;
  __shared__ float4 wlds[4*3*4];     // [tap][c][ci4]
  int cls = blockIdx.x & 3;
  int pxb = blockIdx.x >> 2;
  int pm = cls >> 1, pn = cls & 1;
  int NTI = (pm == 0) ? 2 : 1;
  int NTJ = (pn == 0) ? 2 : 1;
  int NT = NTI*NTJ;
  if (threadIdx.x < NT*3*4) {
    int e = threadIdx.x;
    int tl = e / 12, rem = e % 12;
    int c = rem / 4, ci4 = rem % 4;
    int ki = pm + 2*(tl / NTJ), kj = pn + 2*(tl % NTJ);
    wlds[e] = *(const float4*)(w + ((size_t)(ki*3+kj)*3 + c)*CIN + ci4*4);
  }
  __syncthreads();
  int t = pxb*256 + threadIdx.x;
  int nx = t % HIN, my = (t/HIN) % HIN, bb = t/(HIN*HIN);
  float a0 = bias[0], a1 = bias[1], a2 = bias[2];
  #pragma unroll 1
  for (int ti=0; ti<NTI; ++ti) {
    #pragma unroll 1
    for (int tj=0; tj<NTJ; ++tj) {
      int tl = ti*NTJ + tj;
      int i = my - ti, j = nx - tj;
      if (i >= 0 && j >= 0) {
        const float* bp = in + ((size_t)(bb*HIN + i)*HIN + j)*CIN;
        #pragma unroll
        for (int ci4=0; ci4<4; ++ci4) {
          float4 v = *(const float4*)(bp + ci4*4);
          float4 sc = *(const float4*)(ss + ci4*4);
          float4 sh = *(const float4*)(ss + CIN + ci4*4);
          v.x = fmaxf(0.f, fmaf(v.x, sc.x, sh.x));
          v.y = fmaxf(0.f, fmaf(v.y, sc.y, sh.y));
          v.z = fmaxf(0.f, fmaf(v.z, sc.z, sh.z));
          v.w = fmaxf(0.f, fmaf(v.w, sc.w, sh.w));
          float4 w0 = wlds[(tl*3 + 0)*4 + ci4];
          float4 w1 = wlds[(tl*3 + 1)*4 + ci4];
          float4 w2 = wlds[(tl*3 + 2)*4 + ci4];
          a0 = fmaf(v.x, w0.x, a0); a0 = fmaf(v.y, w0.y, a0);
          a0 = fmaf(v.z, w0.z, a0); a0 = fmaf(v.w, w0.w, a0);
          a1 = fmaf(v.x, w1.x, a1); a1 = fmaf(v.y, w1.y, a1);
          a1 = fmaf(v.z, w1.z, a1); a1 = fmaf(v.w, w1.w, a1);
          a2 = fmaf(v.x, w2.x, a2); a2 = fmaf(v.y, w2.y, a2);
          a2 = fmaf(v.z, w2.z, a2); a2 = fmaf(v.w, w2.w, a2);
        }
      }
    }
  }
  int m = 2*my + pm, n = 2*nx + pn;
  float* op = out + ((size_t)(bb*HOUT + m)*HOUT + n)*3;
  op[0] = fminf(fmaxf(a0, 1e-12f), 1.0f);
  op[1] = fminf(fmaxf(a1, 1e-12f), 1.0f);
  op[2] = fminf(fmaxf(a2, 1e-12f), 1.0f);
}

extern "C" void kernel_launch(void* const* d_in, const int* in_sizes, int n_in,
                              void* d_out, int out_size, void* d_ws, size_t ws_size,
                              hipStream_t stream) {
  const float* x    = (const float*)d_in[0];
  const float* w_e1 = (const float*)d_in[1];
  const float* b_e1 = (const float*)d_in[2];
  const float* g1   = (const float*)d_in[3];
  const float* be1  = (const float*)d_in[4];
  const float* w_e2 = (const float*)d_in[5];
  const float* b_e2 = (const float*)d_in[6];
  const float* g2   = (const float*)d_in[7];
  const float* be2  = (const float*)d_in[8];
  const float* w_e3 = (const float*)d_in[9];
  const float* b_e3 = (const float*)d_in[10];
  const float* g3   = (const float*)d_in[11];
  const float* be3  = (const float*)d_in[12];
  const float* wmem = (const float*)d_in[13];
  const float* w_d1 = (const float*)d_in[14];
  const float* b_d1 = (const float*)d_in[15];
  const float* gt1  = (const float*)d_in[16];
  const float* bet1 = (const float*)d_in[17];
  const float* w_d2 = (const float*)d_in[18];
  const float* b_d2 = (const float*)d_in[19];
  const float* gt2  = (const float*)d_in[20];
  const float* bet2 = (const float*)d_in[21];
  const float* w_d3 = (const float*)d_in[22];
  const float* b_d3 = (const float*)d_in[23];
  float* out = (float*)d_out;

  float* ws = (float*)d_ws;
  // U (u=exp bf16, 64 tiles x 16384 p x 32): alive pass1->pass2 only.
  // A (y1/t2) and Cc (y2/t1) alias its head (live ranges disjoint from U's).
  __bf16* U  = (__bf16*)ws;              // 33,554,432 bf16 = 16,777,216 floats
  float* A   = ws;                       // 4,194,304 (alias: y1 enc / t2 dec)
  float* Cc  = ws + 4194304;             // 2,097,152 (alias: y2 enc / t1 dec)
  float* Gz  = ws + 16777216;            // 1,048,576 zhat
  float* E   = Gz + 1048576 + 8388608;   // 1,048,576 y3 raw
  float* bfbase = E + 1048576;
  __bf16* ZH  = (__bf16*)bfbase;                 // 16384*64 each
  __bf16* ZL  = ZH  + 16384*64;
  __bf16* Z2H = ZL  + 16384*64;
  __bf16* Z2L = Z2H + 16384*64;
  __bf16* MH  = Z2L + 16384*64;                  // 2048*64 each, MH/ML/M2H/M2L CONTIGUOUS
  __bf16* ML  = MH  + 2048*64;
  __bf16* M2H = ML  + 2048*64;
  __bf16* M2L = M2H + 2048*64;
  __bf16* MHT = M2L + 2048*64;                   // 64*2048
  __bf16* MLT = MHT + 64*2048;                   // (unused)
  float* PT   = (float*)(MLT + 64*2048);         // 131072 BN partials
  float* SS   = PT + 131072;                     // 256
  float* PM   = SS + 256;                        // 524288 partM [32][16384]
  float* PS   = PM + 524288;                     // 524288 partS
  float* MT   = PS + 524288;                     // 2097152 per-tile max [64][16384][2]
  (void)ws_size; (void)in_sizes; (void)n_in; (void)out_size;

  // ---- encoder ----
  k_conv1<<<1024,256,0,stream>>>(x, w_e1, b_e1, A, PT);
  k_finalize2<16,1><<<1,256,0,stream>>>(PT, 1024, 1.0/262144.0, g1, be1, SS);
  k_conv_bn<16,32,2,128,64,true><<<512,256,0,stream>>>(A, w_e2, b_e2, SS, Cc, PT);
  k_finalize2<32,2><<<1,256,0,stream>>>(PT, 512, 1.0/65536.0, g2, be2, SS);
  k_conv_bn<32,64,8,64,32,true><<<512,256,0,stream>>>(Cc, w_e3, b_e3, SS, E, PT);
  k_finalize2<64,8><<<1,256,0,stream>>>(PT, 512, 1.0/16384.0, g3, be3, SS);
  // ---- memory addressing (MFMA two-pass; BN3+ReLU fused into prep) ----
  k_prep_mz<<<1152,256,0,stream>>>(wmem, E, SS, MH, ML, M2H, M2L, MHT,
                                   ZH, ZL, Z2H, Z2L);
  k_pass1<<<4096,256,0,stream>>>(MH, ZH, ZL, Z2H, Z2L, U, MT, PM, PS);
  k_pass2<<<512,256,0,stream>>>(U, MT, MHT, PM, PS, Gz);
  // ---- decoder ----
  k_convt_bn<64,32,2,32,false><<<512,256,0,stream>>>(Gz, w_d1, b_d1, nullptr, Cc, PT);
  k_finalize2<32,2><<<1,256,0,stream>>>(PT, 512, 1.0/65536.0, gt1, bet1, SS);
  k_convt_bn<32,16,1,64,true><<<1024,256,0,stream>>>(Cc, w_d2, b_d2, SS, A, PT);
  k_finalize2<16,1><<<1,256,0,stream>>>(PT, 1024, 1.0/262144.0, gt2, bet2, SS);
  k_convt_final<<<4096,256,0,stream>>>(A, w_d3, b_d3, SS, out);
}